// Round 1
// baseline (204.557 us; speedup 1.0000x reference)
//
#include <hip/hip_runtime.h>
#include <stdint.h>
#include <stddef.h>

// Problem constants
#define HB 8
#define HN 1024
#define HC 768
#define HH 12
#define HD 64
#define ROWS (HB*HN)      // 8192
#define BH (HB*HH)        // 96

using s16x4  = __attribute__((ext_vector_type(4))) short;
using bf16x8 = __attribute__((ext_vector_type(8))) short;
using f32x4  = __attribute__((ext_vector_type(4))) float;

__device__ __forceinline__ short f2bf(float f) {
  union { float f; uint32_t u; } c; c.f = f;
  uint32_t u = c.u;
  uint32_t r = (u + 0x7fffu + ((u >> 16) & 1u)) >> 16;   // RNE
  return (short)r;
}
__device__ __forceinline__ float bf2f(short s) {
  union { uint32_t u; float f; } c; c.u = ((uint32_t)(uint16_t)s) << 16;
  return c.f;
}
// pack two f32 -> {bf16(a) | bf16(b)<<16} with RNE, via v_perm_b32
__device__ __forceinline__ uint32_t pack_bf16_rne(float a, float b) {
  union { float f; uint32_t u; } ca, cb; ca.f = a; cb.f = b;
  uint32_t ra = ca.u + 0x7fffu + ((ca.u >> 16) & 1u);
  uint32_t rb = cb.u + 0x7fffu + ((cb.u >> 16) & 1u);
  return __builtin_amdgcn_perm(rb, ra, 0x07060302);  // {rb[31:16], ra[31:16]}
}
__device__ __forceinline__ float fast_exp2(float x) {
#if __has_builtin(__builtin_amdgcn_exp2f)
  return __builtin_amdgcn_exp2f(x);
#else
  return exp2f(x);
#endif
}
__device__ __forceinline__ f32x4 mfma16(bf16x8 a, bf16x8 b, f32x4 c) {
  return __builtin_amdgcn_mfma_f32_16x16x32_bf16(a, b, c, 0, 0, 0);
}
// async global->LDS, 16B per lane. LDS dest MUST be wave-uniform base + lane*16.
__device__ __forceinline__ void gll16(const void* g, void* l) {
  __builtin_amdgcn_global_load_lds((const __attribute__((address_space(1))) void*)g,
                                   (__attribute__((address_space(3))) void*)l,
                                   16, 0, 0);
}

// ---------------- fused f32 -> bf16 convert for all 3 inputs ----------------
__global__ void cvt3_kernel(const float* __restrict__ x,  short* __restrict__ xb,  int n0,
                            const float* __restrict__ wq, short* __restrict__ wqb, int n1,
                            const float* __restrict__ wp, short* __restrict__ wpb, int n2) {
  int i = blockIdx.x * 256 + threadIdx.x;        // index in float4 units
  const float* in; short* out;
  if (i < n0)            { in = x;  out = xb;  }
  else if (i < n0 + n1)  { i -= n0; in = wq; out = wqb; }
  else if (i < n0 + n1 + n2) { i -= n0 + n1; in = wp; out = wpb; }
  else return;
  float4 v = ((const float4*)in)[i];
  s16x4 o;
  o.x = f2bf(v.x); o.y = f2bf(v.y); o.z = f2bf(v.z); o.w = f2bf(v.w);
  ((s16x4*)out)[i] = o;
}

__device__ __forceinline__ void store_c(float* p, float v) { *p = v; }
__device__ __forceinline__ void store_c(short* p, float v) { *p = f2bf(v); }

// ---------------- GEMM 1: qkv = x*Wqkv^T, 256^2 deep-pipelined --------------
// R10: 8-phase-style schedule (T2+T3+T4+T5 per catalog). BK=32, 4 LDS slots
// (A,B each 4x[256][32] bf16 = 128 KiB), staging 3 K-tiles ahead, counted
// vmcnt(8) once per K-tile (never 0 in main loop; tail 8->4->0).
// 512 thr / 8 waves (2Mx4N), per-wave 128x64 out, acc[8][4].
// LDS swizzle: source col-block cb ^ ((r>>1)&3), same XOR on read (rule #21);
// spreads a quad's 16 lanes over 8 distinct 16B slots (2-way = free).
// FP accumulation order identical to R6/R9 kernel (k = 0,32,64,... per acc).
template<int VM, bool STG>
__device__ __forceinline__ void qkv_ktstep(
    int kt, short* sA, short* sB,
    const short* Ag, const short* Bg,
    int wr, int wc, int quad, int lc,
    int c0, int c1, int r0, int r1, int sc0, int sc1,
    f32x4 (&acc)[8][4])
{
  const short* sa = sA + (kt & 3) * 8192;      // 256*32
  const short* sb = sB + (kt & 3) * 8192;
  short* dA = sA + ((kt + 3) & 3) * 8192;      // slot freed at end of kt-1
  short* dB = sB + ((kt + 3) & 3) * 8192;
  const int kcol = (kt + 3) * 32;

  bf16x8 bfr[4], af[4];
  // ---- phase 0: B frags (reused across both phases) + A half 0 ----
#pragma unroll
  for (int nt = 0; nt < 4; ++nt) {
    const int rB = wc*64 + nt*16 + lc;
    bfr[nt] = *(const bf16x8*)(sb + rB*32 + (quad ^ ((rB >> 1) & 3))*8);
  }
#pragma unroll
  for (int mt = 0; mt < 4; ++mt) {
    const int rA = wr*128 + mt*16 + lc;
    af[mt] = *(const bf16x8*)(sa + rA*32 + (quad ^ ((rA >> 1) & 3))*8);
  }
  if constexpr (STG) {   // stage A of K-tile kt+3 (one 16KB half-tile)
    gll16(Ag + (size_t)r0*HC + kcol + sc0, (void*)(dA + c0*8));
    gll16(Ag + (size_t)r1*HC + kcol + sc1, (void*)(dA + c1*8));
  }
  asm volatile("s_barrier" ::: "memory");
  __builtin_amdgcn_s_setprio(1);
#pragma unroll
  for (int mt = 0; mt < 4; ++mt)
#pragma unroll
    for (int nt = 0; nt < 4; ++nt)
      acc[mt][nt] = mfma16(af[mt], bfr[nt], acc[mt][nt]);
  __builtin_amdgcn_s_setprio(0);
  asm volatile("s_barrier" ::: "memory");
  // ---- phase 1: A half 1 ----
#pragma unroll
  for (int mt = 0; mt < 4; ++mt) {
    const int rA = wr*128 + 64 + mt*16 + lc;
    af[mt] = *(const bf16x8*)(sa + rA*32 + (quad ^ ((rA >> 1) & 3))*8);
  }
  if constexpr (STG) {   // stage B of K-tile kt+3
    gll16(Bg + (size_t)r0*HC + kcol + sc0, (void*)(dB + c0*8));
    gll16(Bg + (size_t)r1*HC + kcol + sc1, (void*)(dB + c1*8));
  }
  asm volatile("s_barrier" ::: "memory");
  __builtin_amdgcn_s_setprio(1);
#pragma unroll
  for (int mt = 0; mt < 4; ++mt)
#pragma unroll
    for (int nt = 0; nt < 4; ++nt)
      acc[4+mt][nt] = mfma16(af[mt], bfr[nt], acc[4+mt][nt]);
  __builtin_amdgcn_s_setprio(0);
  // counted wait BEFORE the barrier => after the barrier, every wave's loads
  // older than the newest VM are landed -> cross-wave safe for kt+1 reads.
  if constexpr (VM == 8)      asm volatile("s_waitcnt vmcnt(8)" ::: "memory");
  else if constexpr (VM == 4) asm volatile("s_waitcnt vmcnt(4)" ::: "memory");
  else if constexpr (VM == 0) asm volatile("s_waitcnt vmcnt(0)" ::: "memory");
  asm volatile("s_barrier" ::: "memory");
}

__global__ __launch_bounds__(512, 2) void gemm_qkv(const short* __restrict__ A,
                                                   const short* __restrict__ Bw,
                                                   short* __restrict__ Qb,
                                                   short* __restrict__ Kb,
                                                   short* __restrict__ vb) {
  __shared__ short As[4*256*32];   // 64 KiB
  __shared__ short Bs[4*256*32];   // 64 KiB
  // XCD-bijective swizzle: 288 wgs = 8 XCDs x 36 (4 m-panels x 9 n) each.
  const int wg = blockIdx.x;
  const int swz = (wg & 7)*36 + (wg >> 3);
  const int bx = swz % 9, by = swz / 9;
  const int m0 = by*256, n0 = bx*256;
  const int tid = threadIdx.x;
  const int lane = tid & 63, w = tid >> 6, quad = lane >> 4, lc = lane & 15;
  const int wr = w >> 2, wc = w & 3;           // 2 x 4 wave grid
  // staging chunk ids: c in [0,1024), r=c>>2 row, cb=c&3 col-block of 8
  const int c0 = tid, c1 = 512 + tid;
  const int r0 = c0 >> 2, cb0 = c0 & 3;
  const int r1 = c1 >> 2, cb1 = c1 & 3;
  const int sc0 = (cb0 ^ ((r0 >> 1) & 3))*8;   // pre-swizzled source col
  const int sc1 = (cb1 ^ ((r1 >> 1) & 3))*8;
  const short* Ag = A  + (size_t)m0*HC;
  const short* Bg = Bw + (size_t)n0*HC;
  f32x4 acc[8][4] = {};

  // prologue: stage K-tiles 0,1,2 (12 loads/thread); wait oldest 4 (= kt0)
#pragma unroll
  for (int pk = 0; pk < 3; ++pk) {
    gll16(Ag + (size_t)r0*HC + pk*32 + sc0, (void*)(As + pk*8192 + c0*8));
    gll16(Ag + (size_t)r1*HC + pk*32 + sc1, (void*)(As + pk*8192 + c1*8));
    gll16(Bg + (size_t)r0*HC + pk*32 + sc0, (void*)(Bs + pk*8192 + c0*8));
    gll16(Bg + (size_t)r1*HC + pk*32 + sc1, (void*)(Bs + pk*8192 + c1*8));
  }
  asm volatile("s_waitcnt vmcnt(8)" ::: "memory");
  asm volatile("s_barrier" ::: "memory");

#pragma unroll 1
  for (int kt = 0; kt < 21; ++kt)   // last staged tile: 20+3 = 23
    qkv_ktstep<8,true >(kt, As, Bs, Ag, Bg, wr, wc, quad, lc,
                        c0, c1, r0, r1, sc0, sc1, acc);
  qkv_ktstep<4,false>(21, As, Bs, Ag, Bg, wr, wc, quad, lc,
                      c0, c1, r0, r1, sc0, sc1, acc);
  qkv_ktstep<0,false>(22, As, Bs, Ag, Bg, wr, wc, quad, lc,
                      c0, c1, r0, r1, sc0, sc1, acc);
  qkv_ktstep<-1,false>(23, As, Bs, Ag, Bg, wr, wc, quad, lc,
                       c0, c1, r0, r1, sc0, sc1, acc);

  // epilogue (C/D: col=nt*16+lc, row=quad*4+r); per-wave 64-col group = 1 head
  const int cg = n0 + wc*64;
  const int t = cg / HC;                // 0=q, 1=k, 2=v
  const int h = (cg % HC) / HD;
  if (t < 2) {
    short* outp = (t == 0) ? Qb : Kb;
    const float sc = (t == 0) ? 0.125f : 1.0f;   // SCALE = 64^-0.5 for q
#pragma unroll
    for (int i = 0; i < 8; ++i)
#pragma unroll
      for (int r = 0; r < 4; ++r) {
        float s1 = (acc[i][0][r] + acc[i][1][r]) + (acc[i][2][r] + acc[i][3][r]);
        float s2 = acc[i][0][r]*acc[i][0][r];
        s2 = __builtin_fmaf(acc[i][1][r], acc[i][1][r], s2);
        s2 = __builtin_fmaf(acc[i][2][r], acc[i][2][r], s2);
        s2 = __builtin_fmaf(acc[i][3][r], acc[i][3][r], s2);
#pragma unroll
        for (int off = 1; off < 16; off <<= 1) {
          s1 += __shfl_xor(s1, off);
          s2 += __shfl_xor(s2, off);
        }
        const float mean = s1 * (1.0f/64.0f);
        const float var  = s2 * (1.0f/64.0f) - mean*mean;
        const float inv  = rsqrtf(var + 1e-5f) * sc;
        const int row = m0 + wr*128 + i*16 + quad*4 + r;
        const int b = row >> 10, n_in = row & 1023;
        short* rowp = outp + ((size_t)(b*HH + h)*HN + n_in)*HD;
#pragma unroll
        for (int nt = 0; nt < 4; ++nt)
          rowp[nt*16 + lc] = f2bf((acc[i][nt][r] - mean) * inv);
      }
  } else {
#pragma unroll
    for (int i = 0; i < 8; ++i)
#pragma unroll
      for (int nt = 0; nt < 4; ++nt)
#pragma unroll
        for (int r = 0; r < 4; ++r) {
          const int row = m0 + wr*128 + i*16 + quad*4 + r;
          const int col = h*HD + nt*16 + lc;
          vb[(size_t)row*HC + col] = f2bf(acc[i][nt][r]);
        }
  }
}

// ---------------- GEMM 2: out = AO * Wproj^T (f32 out) ----------------------
__global__ __launch_bounds__(256) void gemm_bt_f32(const short* __restrict__ A,
                                                   const short* __restrict__ Bw,
                                                   float* __restrict__ C,
                                                   int M, int N, int K) {
  __shared__ short As[128*64];
  __shared__ short Bs[128*64];
  const int m0 = blockIdx.y * 128, n0 = blockIdx.x * 128;
  const int tid = threadIdx.x;
  const int lane = tid & 63, w = tid >> 6, quad = lane >> 4, lc = lane & 15;
  const int wr = w >> 1, wc = w & 1;
  f32x4 acc[4][4] = {};
  for (int kt = 0; kt < K; kt += 64) {
#pragma unroll
    for (int i = 0; i < 4; ++i) {
      const int chunk = i*256 + tid;
      const int r = chunk >> 3, cb = chunk & 7;
      const int cbs = cb ^ (r & 7);
      gll16(A  + (size_t)(m0 + r)*K + kt + cbs*8, (void*)(As + (size_t)chunk*8));
      gll16(Bw + (size_t)(n0 + r)*K + kt + cbs*8, (void*)(Bs + (size_t)chunk*8));
    }
    __syncthreads();
#pragma unroll
    for (int kk = 0; kk < 2; ++kk) {
      bf16x8 af[4], bfr[4];
      const int kb = kk*4 + quad;
#pragma unroll
      for (int mt = 0; mt < 4; ++mt)
        af[mt] = *(const bf16x8*)(As + (wr*64 + mt*16 + lc)*64 + (kb ^ (lc & 7))*8);
#pragma unroll
      for (int nt = 0; nt < 4; ++nt)
        bfr[nt] = *(const bf16x8*)(Bs + (wc*64 + nt*16 + lc)*64 + (kb ^ (lc & 7))*8);
#pragma unroll
      for (int mt = 0; mt < 4; ++mt)
#pragma unroll
        for (int nt = 0; nt < 4; ++nt)
          acc[mt][nt] = mfma16(af[mt], bfr[nt], acc[mt][nt]);
    }
    __syncthreads();
  }
#pragma unroll
  for (int mt = 0; mt < 4; ++mt)
#pragma unroll
    for (int nt = 0; nt < 4; ++nt)
#pragma unroll
      for (int r = 0; r < 4; ++r) {
        const int row = m0 + wr*64 + mt*16 + quad*4 + r;
        const int col = n0 + wc*64 + nt*16 + lc;
        store_c(C + (size_t)row*N + col, acc[mt][nt][r]);
      }
}

// ---------------- V transpose/permute: vb [8192][768] -> Vtb [BH][64][1024] --
// Key-permuted per 64-chunk: storage col c (within 64-group) holds key
// k(c) = (c&3)*16 + (c>>2)  — matches the b64 P stash in attn.
__global__ __launch_bounds__(256) void vtrans_kernel(const short* __restrict__ vb,
                                                     short* __restrict__ Vtb) {
  const int blk = blockIdx.x;            // bh*8 + tile
  const int tile = blk & 7, bh = blk >> 3;
  const int b = bh / HH, h = bh % HH;
  const int n0 = tile * 128;
  const int tid = threadIdx.x;
  __shared__ float vt[128][65];
#pragma unroll
  for (int i = 0; i < 32; ++i) {
    const int idx = i*256 + tid; const int r = idx >> 6, dcol = idx & 63;
    vt[r][dcol] = bf2f(vb[(size_t)(b*HN + n0 + r)*HC + h*HD + dcol]);
  }
  __syncthreads();
#pragma unroll
  for (int it = 0; it < 4; ++it) {
    const int idx = it*256 + tid;
    const int dd = idx >> 4, j8 = idx & 15;   // dd in [0,64), j8 in [0,16)
    bf16x8 o;
#pragma unroll
    for (int u = 0; u < 8; ++u) {
      const int c  = j8*8 + u;                // storage col within 128-tile
      const int g  = c >> 6, cl = c & 63;     // 64-group, col within group
      const int k  = g*64 + ((cl & 3)*16 + (cl >> 2));
      o[u] = f2bf(vt[k][dd]);
    }
    *(bf16x8*)(Vtb + ((size_t)bh*HD + dd)*HN + n0 + j8*8) = o;
  }
}

// ---------------- flash attention: 128 q-rows/block, 64-key chunks ----------
// R9: each wave owns 32 q-rows (2 m-tiles) -> per chunk 32 MFMA + 32 exp
// against the SAME staging cost as R6's 16+16 -> barriers per unit work halve,
// K/V global traffic halves. Grid 768 blocks = 3/CU; LDS 36864 B.
__global__ __launch_bounds__(256, 3) void attn_kernel(const short* __restrict__ Qb,
                                                      const short* __restrict__ Kb,
                                                      const short* __restrict__ Vtb,
                                                      short* __restrict__ AOb) {
  const int blk = blockIdx.x;
  const int qt = blk & 7, bh = blk >> 3;
  const int b = bh / HH, h = bh % HH;
  const int tid = threadIdx.x, w = tid >> 6, lane = tid & 63;
  const int quad = lane >> 4, lc = lane & 15;

  __shared__ short Ks [64][72];      // K chunk: row=key(natural), padded
  __shared__ short Vts[64][72];      // V chunk: row=d, cols=64 keys permuted
  __shared__ short Ps [4][32][72];   // per-wave P stash (32 q-rows), permuted keys

  // Q A-fragments: A[m=lane&15][k=quad*8+j]; wave rows qt*128 + w*32 + mt*16
  bf16x8 aq[2][2];
#pragma unroll
  for (int mt = 0; mt < 2; ++mt) {
    const int mrow = qt*128 + w*32 + mt*16 + lc;
    aq[mt][0] = *(const bf16x8*)(Qb + ((size_t)bh*HN + mrow)*HD + quad*8);
    aq[mt][1] = *(const bf16x8*)(Qb + ((size_t)bh*HN + mrow)*HD + 32 + quad*8);
  }

  const short* kbh = Kb  + (size_t)bh*HN*HD;
  const short* vbh = Vtb + (size_t)bh*HD*HN;

  f32x4 oacc[2][4] = {};
  float l_i[2][4] = {};

  // staging regs: c = i*256+tid in [0,512); row=c>>3 in [0,64), cb=c&7
  bf16x8 gk[2], gv[2];
#pragma unroll
  for (int i = 0; i < 2; ++i) {
    const int c = i*256 + tid;
    gk[i] = *(const bf16x8*)(kbh + (size_t)(c >> 3)*HD + (c & 7)*8);
    gv[i] = *(const bf16x8*)(vbh + (size_t)(c >> 3)*HN + (c & 7)*8);
  }
#pragma unroll
  for (int i = 0; i < 2; ++i) {
    const int c = i*256 + tid;
    *(bf16x8*)(&Ks [c >> 3][(c & 7)*8]) = gk[i];
    *(bf16x8*)(&Vts[c >> 3][(c & 7)*8]) = gv[i];
  }
  __syncthreads();

  const float LOG2E = 1.44269504f;
  const float MB2   = 8.0f * 1.44269504f;   // fixed max * log2(e)

  for (int ck = 0; ck < 16; ++ck) {
    // prefetch chunk ck+1 into registers (overlaps with compute below)
    if (ck < 15) {
      const int nn0 = (ck + 1)*64;
#pragma unroll
      for (int i = 0; i < 2; ++i) {
        const int c = i*256 + tid;
        gk[i] = *(const bf16x8*)(kbh + (size_t)(nn0 + (c >> 3))*HD + (c & 7)*8);
        gv[i] = *(const bf16x8*)(vbh + (size_t)(c >> 3)*HN + nn0 + (c & 7)*8);
      }
    }

    // S = Q K^T : 16 MFMAs (2 m-tiles x 2 kk x 4 nt)
    f32x4 sacc[2][4] = {};
#pragma unroll
    for (int kk = 0; kk < 2; ++kk)
#pragma unroll
      for (int nt = 0; nt < 4; ++nt) {
        bf16x8 bk = *(const bf16x8*)(&Ks[nt*16 + lc][kk*32 + quad*8]);
#pragma unroll
        for (int mt = 0; mt < 2; ++mt)
          sacc[mt][nt] = mfma16(aq[mt][kk], bk, sacc[mt][nt]);
      }

    // fixed-max softmax + P stash (C->A relayout, ds_write_b64 per row)
#pragma unroll
    for (int mt = 0; mt < 2; ++mt)
#pragma unroll
      for (int r = 0; r < 4; ++r) {
        float ps[4];
#pragma unroll
        for (int nt = 0; nt < 4; ++nt) {
          ps[nt] = fast_exp2(__builtin_fmaf(sacc[mt][nt][r], LOG2E, -MB2));
          sacc[mt][nt][r] = ps[nt];
        }
        l_i[mt][r] += (ps[0] + ps[1]) + (ps[2] + ps[3]);
        uint2 pk;
        pk.x = pack_bf16_rne(ps[0], ps[1]);
        pk.y = pack_bf16_rne(ps[2], ps[3]);
        *(uint2*)(&Ps[w][mt*16 + quad*4 + r][lc*4]) = pk;
      }

    // O += P V : 16 MFMAs (A from Ps, B from Vts; both in permuted key space)
#pragma unroll
    for (int kk = 0; kk < 2; ++kk) {
      bf16x8 ap[2];
#pragma unroll
      for (int mt = 0; mt < 2; ++mt)
        ap[mt] = *(const bf16x8*)(&Ps[w][mt*16 + lc][kk*32 + quad*8]);
#pragma unroll
      for (int nt2 = 0; nt2 < 4; ++nt2) {
        bf16x8 bv = *(const bf16x8*)(&Vts[nt2*16 + lc][kk*32 + quad*8]);
#pragma unroll
        for (int mt = 0; mt < 2; ++mt)
          oacc[mt][nt2] = mfma16(ap[mt], bv, oacc[mt][nt2]);
      }
    }

    if (ck < 15) {
      __syncthreads();   // all waves done reading Ks/Vts
#pragma unroll
      for (int i = 0; i < 2; ++i) {
        const int c = i*256 + tid;
        *(bf16x8*)(&Ks [c >> 3][(c & 7)*8]) = gk[i];
        *(bf16x8*)(&Vts[c >> 3][(c & 7)*8]) = gv[i];
      }
      __syncthreads();
    }
  }

  // epilogue: reduce l across the 16 lanes of each quad, then scale & store
#pragma unroll
  for (int mt = 0; mt < 2; ++mt)
#pragma unroll
    for (int r = 0; r < 4; ++r) {
      float l = l_i[mt][r];
#pragma unroll
      for (int off = 1; off < 16; off <<= 1) l += __shfl_xor(l, off);
      const float rl = 1.0f / l;
      const int row = qt*128 + w*32 + mt*16 + quad*4 + r;
#pragma unroll
      for (int nt2 = 0; nt2 < 4; ++nt2) {
        const int d = nt2*16 + lc;
        AOb[((size_t)(b*HN + row))*HC + h*HD + d] = f2bf(oacc[mt][nt2][r] * rl);
      }
    }
}

// ---------------- launch ----------------
extern "C" void kernel_launch(void* const* d_in, const int* in_sizes, int n_in,
                              void* d_out, int out_size, void* d_ws, size_t ws_size,
                              hipStream_t stream) {
  const float* x     = (const float*)d_in[0];
  const float* wqkv  = (const float*)d_in[1];
  const float* wproj = (const float*)d_in[2];
  float* out = (float*)d_out;

  char* ws = (char*)d_ws;
  size_t off = 0;
  auto alloc = [&](size_t bytes) -> void* {
    void* p = ws + off; off += (bytes + 255) & ~(size_t)255; return p;
  };
  short* xb     = (short*)alloc((size_t)ROWS*HC*2);        // 12.6 MB
  short* wqkvb  = (short*)alloc((size_t)3*HC*HC*2);        //  3.5 MB
  short* wprojb = (short*)alloc((size_t)HC*HC*2);          //  1.2 MB
  short* vb     = (short*)alloc((size_t)ROWS*HC*2);        // 12.6 MB
  short* Qb     = (short*)alloc((size_t)BH*HN*HD*2);       // 12.6 MB
  short* Kb     = (short*)alloc((size_t)BH*HN*HD*2);       // 12.6 MB
  short* Vtb    = (short*)alloc((size_t)BH*HD*HN*2);       // 12.6 MB
  short* AOb    = (short*)alloc((size_t)ROWS*HC*2);        // 12.6 MB  (~80 MB total)

  { const int n0 = ROWS*HC/4, n1 = 3*HC*HC/4, n2 = HC*HC/4;
    const int tot = n0 + n1 + n2;
    cvt3_kernel<<<(tot + 255)/256, 256, 0, stream>>>(x, xb, n0, wqkv, wqkvb, n1,
                                                     wproj, wprojb, n2); }

  // 288 = 9 n-blocks x 32 m-blocks, XCD-swizzled inside the kernel
  gemm_qkv<<<dim3(288), 512, 0, stream>>>(xb, wqkvb, Qb, Kb, vb);
  vtrans_kernel<<<BH*8, 256, 0, stream>>>(vb, Vtb);
  attn_kernel<<<BH*8, 256, 0, stream>>>(Qb, Kb, Vtb, AOb);
  gemm_bt_f32<<<dim3(HC/128, ROWS/128), 256, 0, stream>>>(AOb, wprojb, out,
                                                          ROWS, HC, HC);
}

// Round 2
// 200.365 us; speedup vs baseline: 1.0209x; 1.0209x over previous
//
#include <hip/hip_runtime.h>
#include <stdint.h>
#include <stddef.h>

// Problem constants
#define HB 8
#define HN 1024
#define HC 768
#define HH 12
#define HD 64
#define ROWS (HB*HN)      // 8192
#define BH (HB*HH)        // 96

using s16x4  = __attribute__((ext_vector_type(4))) short;
using bf16x8 = __attribute__((ext_vector_type(8))) short;
using f32x4  = __attribute__((ext_vector_type(4))) float;

__device__ __forceinline__ short f2bf(float f) {
  union { float f; uint32_t u; } c; c.f = f;
  uint32_t u = c.u;
  uint32_t r = (u + 0x7fffu + ((u >> 16) & 1u)) >> 16;   // RNE
  return (short)r;
}
__device__ __forceinline__ float bf2f(short s) {
  union { uint32_t u; float f; } c; c.u = ((uint32_t)(uint16_t)s) << 16;
  return c.f;
}
// pack two f32 -> {bf16(a) | bf16(b)<<16} with RNE, via v_perm_b32
__device__ __forceinline__ uint32_t pack_bf16_rne(float a, float b) {
  union { float f; uint32_t u; } ca, cb; ca.f = a; cb.f = b;
  uint32_t ra = ca.u + 0x7fffu + ((ca.u >> 16) & 1u);
  uint32_t rb = cb.u + 0x7fffu + ((cb.u >> 16) & 1u);
  return __builtin_amdgcn_perm(rb, ra, 0x07060302);  // {rb[31:16], ra[31:16]}
}
__device__ __forceinline__ float fast_exp2(float x) {
#if __has_builtin(__builtin_amdgcn_exp2f)
  return __builtin_amdgcn_exp2f(x);
#else
  return exp2f(x);
#endif
}
__device__ __forceinline__ f32x4 mfma16(bf16x8 a, bf16x8 b, f32x4 c) {
  return __builtin_amdgcn_mfma_f32_16x16x32_bf16(a, b, c, 0, 0, 0);
}
// async global->LDS, 16B per lane. LDS dest MUST be wave-uniform base + lane*16.
__device__ __forceinline__ void gll16(const void* g, void* l) {
  __builtin_amdgcn_global_load_lds((const __attribute__((address_space(1))) void*)g,
                                   (__attribute__((address_space(3))) void*)l,
                                   16, 0, 0);
}

// ---------------- fused f32 -> bf16 convert for all 3 inputs ----------------
__global__ void cvt3_kernel(const float* __restrict__ x,  short* __restrict__ xb,  int n0,
                            const float* __restrict__ wq, short* __restrict__ wqb, int n1,
                            const float* __restrict__ wp, short* __restrict__ wpb, int n2) {
  int i = blockIdx.x * 256 + threadIdx.x;        // index in float4 units
  const float* in; short* out;
  if (i < n0)            { in = x;  out = xb;  }
  else if (i < n0 + n1)  { i -= n0; in = wq; out = wqb; }
  else if (i < n0 + n1 + n2) { i -= n0 + n1; in = wp; out = wpb; }
  else return;
  float4 v = ((const float4*)in)[i];
  s16x4 o;
  o.x = f2bf(v.x); o.y = f2bf(v.y); o.z = f2bf(v.z); o.w = f2bf(v.w);
  ((s16x4*)out)[i] = o;
}

__device__ __forceinline__ void store_c(float* p, float v) { *p = v; }
__device__ __forceinline__ void store_c(short* p, float v) { *p = f2bf(v); }

// ---------------- GEMM 1: qkv = x*Wqkv^T ------------------------------------
// R11: fix R10's grid quantization (288 blocks @ 1 block/CU = 2 rounds, tail
// wasted 44%). New config keeps the counted-vmcnt pipeline but restores
// 2 blocks/CU residency:
//   BM=256 BN=128 BK=32, 512 thr (8 waves, 4Mx2N), per-wave 64x64 (acc 64 reg)
//   3 LDS slots (A 16KB + B 8KB each) = 72 KiB  -> 2 blocks/CU (<=80KB, <=128r)
//   2-deep staging, ONE barrier + ONE vmcnt(3) per K-tile (never 0 until tail)
//   grid 576 = 32m x 18n, XCD-bijective swizzle (72/XCD, m-panel contiguous)
// FP accumulation order identical to R9/R10 (K ascending, 32-steps).
template<int VM, bool STG, int SLOT>
__device__ __forceinline__ void qkv_ktile(
    int kt, short* sA, short* sB,
    const short* Ag, const short* Bg,
    int wr, int wc, int quad, int lc,
    int aoff0, int aoff1, int boff0,      // per-thread source offsets (row*HC+swz-col)
    int cA0, int cA1, int cB0,            // per-thread LDS chunk ids
    f32x4 (&acc)[4][4])
{
  // T(kt) landed for THIS wave; barrier makes it true for ALL waves.
  if constexpr (VM == 3) asm volatile("s_waitcnt vmcnt(3)" ::: "memory");
  else                   asm volatile("s_waitcnt vmcnt(0)" ::: "memory");
  __builtin_amdgcn_s_barrier();
  // After the barrier every wave finished iteration kt-1 (incl. its ds_reads
  // of slot (kt-1)%3) -> safe to stage kt+2 into that slot.
  if constexpr (STG) {
    constexpr int DST = (SLOT + 2) % 3;
    const int kcol = (kt + 2) * 32;
    short* dA = sA + DST*8192;
    short* dB = sB + DST*4096;
    gll16(Ag + (size_t)(aoff0 + kcol), (void*)(dA + cA0*8));
    gll16(Ag + (size_t)(aoff1 + kcol), (void*)(dA + cA1*8));
    gll16(Bg + (size_t)(boff0 + kcol), (void*)(dB + cB0*8));
  }
  const short* sa = sA + SLOT*8192;
  const short* sb = sB + SLOT*4096;
  bf16x8 af[4], bfr[4];
#pragma unroll
  for (int mt = 0; mt < 4; ++mt) {
    const int rA = wr*64 + mt*16 + lc;
    af[mt] = *(const bf16x8*)(sa + rA*32 + (quad ^ ((rA >> 1) & 3))*8);
  }
#pragma unroll
  for (int nt = 0; nt < 4; ++nt) {
    const int rB = wc*64 + nt*16 + lc;
    bfr[nt] = *(const bf16x8*)(sb + rB*32 + (quad ^ ((rB >> 1) & 3))*8);
  }
  __builtin_amdgcn_s_setprio(1);
#pragma unroll
  for (int mt = 0; mt < 4; ++mt)
#pragma unroll
    for (int nt = 0; nt < 4; ++nt)
      acc[mt][nt] = mfma16(af[mt], bfr[nt], acc[mt][nt]);
  __builtin_amdgcn_s_setprio(0);
}

__global__ __launch_bounds__(512, 4) void gemm_qkv(const short* __restrict__ A,
                                                   const short* __restrict__ Bw,
                                                   short* __restrict__ Qb,
                                                   short* __restrict__ Kb,
                                                   short* __restrict__ vb) {
  __shared__ short As[3*256*32];   // 48 KiB
  __shared__ short Bs[3*128*32];   // 24 KiB
  // XCD-bijective swizzle: 576 wgs = 8 XCDs x 72 (4 m-panels x 18 n) each.
  const int wg = blockIdx.x;
  const int swz = (wg & 7)*72 + (wg >> 3);
  const int by = swz / 18, bx = swz % 18;
  const int m0 = by*256, n0 = bx*128;
  const int tid = threadIdx.x;
  const int lane = tid & 63, w = tid >> 6, quad = lane >> 4, lc = lane & 15;
  const int wr = w >> 1, wc = w & 1;           // 4 x 2 wave grid
  // staging: A tile 256x32 = 1024 16B-chunks (2/thread); B 128x32 = 512 (1/thread)
  // chunk c: r = c>>2, cb = c&3; source col pre-swizzled cb ^ ((r>>1)&3)
  const int cA0 = tid,        rA0 = cA0 >> 2, sbA0 = ((cA0 & 3) ^ ((rA0 >> 1) & 3))*8;
  const int cA1 = 512 + tid,  rA1 = cA1 >> 2, sbA1 = ((cA1 & 3) ^ ((rA1 >> 1) & 3))*8;
  const int cB0 = tid,        rB0 = cB0 >> 2, sbB0 = ((cB0 & 3) ^ ((rB0 >> 1) & 3))*8;
  const int aoff0 = rA0*HC + sbA0;
  const int aoff1 = rA1*HC + sbA1;
  const int boff0 = rB0*HC + sbB0;
  const short* Ag = A  + (size_t)m0*HC;
  const short* Bg = Bw + (size_t)n0*HC;
  f32x4 acc[4][4] = {};

  // prologue: stage K-tiles 0 and 1 (FIFO order: T0's 3 loads, then T1's 3)
#pragma unroll
  for (int pk = 0; pk < 2; ++pk) {
    gll16(Ag + (size_t)(aoff0 + pk*32), (void*)(As + pk*8192 + cA0*8));
    gll16(Ag + (size_t)(aoff1 + pk*32), (void*)(As + pk*8192 + cA1*8));
    gll16(Bg + (size_t)(boff0 + pk*32), (void*)(Bs + pk*4096 + cB0*8));
  }

  // main loop: 24 K-tiles, unrolled by 3 so the slot index is compile-time
#pragma unroll 1
  for (int kt = 0; kt < 21; kt += 3) {
    qkv_ktile<3,true,0>(kt,   As, Bs, Ag, Bg, wr, wc, quad, lc,
                        aoff0, aoff1, boff0, cA0, cA1, cB0, acc);
    qkv_ktile<3,true,1>(kt+1, As, Bs, Ag, Bg, wr, wc, quad, lc,
                        aoff0, aoff1, boff0, cA0, cA1, cB0, acc);
    qkv_ktile<3,true,2>(kt+2, As, Bs, Ag, Bg, wr, wc, quad, lc,
                        aoff0, aoff1, boff0, cA0, cA1, cB0, acc);
  }
  qkv_ktile<3,true ,0>(21, As, Bs, Ag, Bg, wr, wc, quad, lc,
                       aoff0, aoff1, boff0, cA0, cA1, cB0, acc);   // stages T23
  qkv_ktile<3,false,1>(22, As, Bs, Ag, Bg, wr, wc, quad, lc,
                       aoff0, aoff1, boff0, cA0, cA1, cB0, acc);
  qkv_ktile<0,false,2>(23, As, Bs, Ag, Bg, wr, wc, quad, lc,
                       aoff0, aoff1, boff0, cA0, cA1, cB0, acc);

  // epilogue (C/D: col=nt*16+lc, row=quad*4+r); per-wave 64-col group = 1 head
  const int cg = n0 + wc*64;
  const int t = cg / HC;                // 0=q, 1=k, 2=v
  const int h = (cg % HC) / HD;
  if (t < 2) {
    short* outp = (t == 0) ? Qb : Kb;
    const float sc = (t == 0) ? 0.125f : 1.0f;   // SCALE = 64^-0.5 for q
#pragma unroll
    for (int i = 0; i < 4; ++i)
#pragma unroll
      for (int r = 0; r < 4; ++r) {
        float s1 = (acc[i][0][r] + acc[i][1][r]) + (acc[i][2][r] + acc[i][3][r]);
        float s2 = acc[i][0][r]*acc[i][0][r];
        s2 = __builtin_fmaf(acc[i][1][r], acc[i][1][r], s2);
        s2 = __builtin_fmaf(acc[i][2][r], acc[i][2][r], s2);
        s2 = __builtin_fmaf(acc[i][3][r], acc[i][3][r], s2);
#pragma unroll
        for (int off = 1; off < 16; off <<= 1) {
          s1 += __shfl_xor(s1, off);
          s2 += __shfl_xor(s2, off);
        }
        const float mean = s1 * (1.0f/64.0f);
        const float var  = s2 * (1.0f/64.0f) - mean*mean;
        const float inv  = rsqrtf(var + 1e-5f) * sc;
        const int row = m0 + wr*64 + i*16 + quad*4 + r;
        const int b = row >> 10, n_in = row & 1023;
        short* rowp = outp + ((size_t)(b*HH + h)*HN + n_in)*HD;
#pragma unroll
        for (int nt = 0; nt < 4; ++nt)
          rowp[nt*16 + lc] = f2bf((acc[i][nt][r] - mean) * inv);
      }
  } else {
#pragma unroll
    for (int i = 0; i < 4; ++i)
#pragma unroll
      for (int nt = 0; nt < 4; ++nt)
#pragma unroll
        for (int r = 0; r < 4; ++r) {
          const int row = m0 + wr*64 + i*16 + quad*4 + r;
          const int col = h*HD + nt*16 + lc;
          vb[(size_t)row*HC + col] = f2bf(acc[i][nt][r]);
        }
  }
}

// ---------------- GEMM 2: out = AO * Wproj^T (f32 out) ----------------------
__global__ __launch_bounds__(256) void gemm_bt_f32(const short* __restrict__ A,
                                                   const short* __restrict__ Bw,
                                                   float* __restrict__ C,
                                                   int M, int N, int K) {
  __shared__ short As[128*64];
  __shared__ short Bs[128*64];
  const int m0 = blockIdx.y * 128, n0 = blockIdx.x * 128;
  const int tid = threadIdx.x;
  const int lane = tid & 63, w = tid >> 6, quad = lane >> 4, lc = lane & 15;
  const int wr = w >> 1, wc = w & 1;
  f32x4 acc[4][4] = {};
  for (int kt = 0; kt < K; kt += 64) {
#pragma unroll
    for (int i = 0; i < 4; ++i) {
      const int chunk = i*256 + tid;
      const int r = chunk >> 3, cb = chunk & 7;
      const int cbs = cb ^ (r & 7);
      gll16(A  + (size_t)(m0 + r)*K + kt + cbs*8, (void*)(As + (size_t)chunk*8));
      gll16(Bw + (size_t)(n0 + r)*K + kt + cbs*8, (void*)(Bs + (size_t)chunk*8));
    }
    __syncthreads();
#pragma unroll
    for (int kk = 0; kk < 2; ++kk) {
      bf16x8 af[4], bfr[4];
      const int kb = kk*4 + quad;
#pragma unroll
      for (int mt = 0; mt < 4; ++mt)
        af[mt] = *(const bf16x8*)(As + (wr*64 + mt*16 + lc)*64 + (kb ^ (lc & 7))*8);
#pragma unroll
      for (int nt = 0; nt < 4; ++nt)
        bfr[nt] = *(const bf16x8*)(Bs + (wc*64 + nt*16 + lc)*64 + (kb ^ (lc & 7))*8);
#pragma unroll
      for (int mt = 0; mt < 4; ++mt)
#pragma unroll
        for (int nt = 0; nt < 4; ++nt)
          acc[mt][nt] = mfma16(af[mt], bfr[nt], acc[mt][nt]);
    }
    __syncthreads();
  }
#pragma unroll
  for (int mt = 0; mt < 4; ++mt)
#pragma unroll
    for (int nt = 0; nt < 4; ++nt)
#pragma unroll
      for (int r = 0; r < 4; ++r) {
        const int row = m0 + wr*64 + mt*16 + quad*4 + r;
        const int col = n0 + wc*64 + nt*16 + lc;
        store_c(C + (size_t)row*N + col, acc[mt][nt][r]);
      }
}

// ---------------- V transpose/permute: vb [8192][768] -> Vtb [BH][64][1024] --
// Key-permuted per 64-chunk: storage col c (within 64-group) holds key
// k(c) = (c&3)*16 + (c>>2)  — matches the b64 P stash in attn.
__global__ __launch_bounds__(256) void vtrans_kernel(const short* __restrict__ vb,
                                                     short* __restrict__ Vtb) {
  const int blk = blockIdx.x;            // bh*8 + tile
  const int tile = blk & 7, bh = blk >> 3;
  const int b = bh / HH, h = bh % HH;
  const int n0 = tile * 128;
  const int tid = threadIdx.x;
  __shared__ float vt[128][65];
#pragma unroll
  for (int i = 0; i < 32; ++i) {
    const int idx = i*256 + tid; const int r = idx >> 6, dcol = idx & 63;
    vt[r][dcol] = bf2f(vb[(size_t)(b*HN + n0 + r)*HC + h*HD + dcol]);
  }
  __syncthreads();
#pragma unroll
  for (int it = 0; it < 4; ++it) {
    const int idx = it*256 + tid;
    const int dd = idx >> 4, j8 = idx & 15;   // dd in [0,64), j8 in [0,16)
    bf16x8 o;
#pragma unroll
    for (int u = 0; u < 8; ++u) {
      const int c  = j8*8 + u;                // storage col within 128-tile
      const int g  = c >> 6, cl = c & 63;     // 64-group, col within group
      const int k  = g*64 + ((cl & 3)*16 + (cl >> 2));
      o[u] = f2bf(vt[k][dd]);
    }
    *(bf16x8*)(Vtb + ((size_t)bh*HD + dd)*HN + n0 + j8*8) = o;
  }
}

// ---------------- flash attention: 128 q-rows/block, 64-key chunks ----------
// R9: each wave owns 32 q-rows (2 m-tiles) -> per chunk 32 MFMA + 32 exp
// against the SAME staging cost as R6's 16+16 -> barriers per unit work halve,
// K/V global traffic halves. Grid 768 blocks = 3/CU; LDS 36864 B.
__global__ __launch_bounds__(256, 3) void attn_kernel(const short* __restrict__ Qb,
                                                      const short* __restrict__ Kb,
                                                      const short* __restrict__ Vtb,
                                                      short* __restrict__ AOb) {
  const int blk = blockIdx.x;
  const int qt = blk & 7, bh = blk >> 3;
  const int b = bh / HH, h = bh % HH;
  const int tid = threadIdx.x, w = tid >> 6, lane = tid & 63;
  const int quad = lane >> 4, lc = lane & 15;

  __shared__ short Ks [64][72];      // K chunk: row=key(natural), padded
  __shared__ short Vts[64][72];      // V chunk: row=d, cols=64 keys permuted
  __shared__ short Ps [4][32][72];   // per-wave P stash (32 q-rows), permuted keys

  // Q A-fragments: A[m=lane&15][k=quad*8+j]; wave rows qt*128 + w*32 + mt*16
  bf16x8 aq[2][2];
#pragma unroll
  for (int mt = 0; mt < 2; ++mt) {
    const int mrow = qt*128 + w*32 + mt*16 + lc;
    aq[mt][0] = *(const bf16x8*)(Qb + ((size_t)bh*HN + mrow)*HD + quad*8);
    aq[mt][1] = *(const bf16x8*)(Qb + ((size_t)bh*HN + mrow)*HD + 32 + quad*8);
  }

  const short* kbh = Kb  + (size_t)bh*HN*HD;
  const short* vbh = Vtb + (size_t)bh*HD*HN;

  f32x4 oacc[2][4] = {};
  float l_i[2][4] = {};

  // staging regs: c = i*256+tid in [0,512); row=c>>3 in [0,64), cb=c&7
  bf16x8 gk[2], gv[2];
#pragma unroll
  for (int i = 0; i < 2; ++i) {
    const int c = i*256 + tid;
    gk[i] = *(const bf16x8*)(kbh + (size_t)(c >> 3)*HD + (c & 7)*8);
    gv[i] = *(const bf16x8*)(vbh + (size_t)(c >> 3)*HN + (c & 7)*8);
  }
#pragma unroll
  for (int i = 0; i < 2; ++i) {
    const int c = i*256 + tid;
    *(bf16x8*)(&Ks [c >> 3][(c & 7)*8]) = gk[i];
    *(bf16x8*)(&Vts[c >> 3][(c & 7)*8]) = gv[i];
  }
  __syncthreads();

  const float LOG2E = 1.44269504f;
  const float MB2   = 8.0f * 1.44269504f;   // fixed max * log2(e)

  for (int ck = 0; ck < 16; ++ck) {
    // prefetch chunk ck+1 into registers (overlaps with compute below)
    if (ck < 15) {
      const int nn0 = (ck + 1)*64;
#pragma unroll
      for (int i = 0; i < 2; ++i) {
        const int c = i*256 + tid;
        gk[i] = *(const bf16x8*)(kbh + (size_t)(nn0 + (c >> 3))*HD + (c & 7)*8);
        gv[i] = *(const bf16x8*)(vbh + (size_t)(c >> 3)*HN + nn0 + (c & 7)*8);
      }
    }

    // S = Q K^T : 16 MFMAs (2 m-tiles x 2 kk x 4 nt)
    f32x4 sacc[2][4] = {};
#pragma unroll
    for (int kk = 0; kk < 2; ++kk)
#pragma unroll
      for (int nt = 0; nt < 4; ++nt) {
        bf16x8 bk = *(const bf16x8*)(&Ks[nt*16 + lc][kk*32 + quad*8]);
#pragma unroll
        for (int mt = 0; mt < 2; ++mt)
          sacc[mt][nt] = mfma16(aq[mt][kk], bk, sacc[mt][nt]);
      }

    // fixed-max softmax + P stash (C->A relayout, ds_write_b64 per row)
#pragma unroll
    for (int mt = 0; mt < 2; ++mt)
#pragma unroll
      for (int r = 0; r < 4; ++r) {
        float ps[4];
#pragma unroll
        for (int nt = 0; nt < 4; ++nt) {
          ps[nt] = fast_exp2(__builtin_fmaf(sacc[mt][nt][r], LOG2E, -MB2));
          sacc[mt][nt][r] = ps[nt];
        }
        l_i[mt][r] += (ps[0] + ps[1]) + (ps[2] + ps[3]);
        uint2 pk;
        pk.x = pack_bf16_rne(ps[0], ps[1]);
        pk.y = pack_bf16_rne(ps[2], ps[3]);
        *(uint2*)(&Ps[w][mt*16 + quad*4 + r][lc*4]) = pk;
      }

    // O += P V : 16 MFMAs (A from Ps, B from Vts; both in permuted key space)
#pragma unroll
    for (int kk = 0; kk < 2; ++kk) {
      bf16x8 ap[2];
#pragma unroll
      for (int mt = 0; mt < 2; ++mt)
        ap[mt] = *(const bf16x8*)(&Ps[w][mt*16 + lc][kk*32 + quad*8]);
#pragma unroll
      for (int nt2 = 0; nt2 < 4; ++nt2) {
        bf16x8 bv = *(const bf16x8*)(&Vts[nt2*16 + lc][kk*32 + quad*8]);
#pragma unroll
        for (int mt = 0; mt < 2; ++mt)
          oacc[mt][nt2] = mfma16(ap[mt], bv, oacc[mt][nt2]);
      }
    }

    if (ck < 15) {
      __syncthreads();   // all waves done reading Ks/Vts
#pragma unroll
      for (int i = 0; i < 2; ++i) {
        const int c = i*256 + tid;
        *(bf16x8*)(&Ks [c >> 3][(c & 7)*8]) = gk[i];
        *(bf16x8*)(&Vts[c >> 3][(c & 7)*8]) = gv[i];
      }
      __syncthreads();
    }
  }

  // epilogue: reduce l across the 16 lanes of each quad, then scale & store
#pragma unroll
  for (int mt = 0; mt < 2; ++mt)
#pragma unroll
    for (int r = 0; r < 4; ++r) {
      float l = l_i[mt][r];
#pragma unroll
      for (int off = 1; off < 16; off <<= 1) l += __shfl_xor(l, off);
      const float rl = 1.0f / l;
      const int row = qt*128 + w*32 + mt*16 + quad*4 + r;
#pragma unroll
      for (int nt2 = 0; nt2 < 4; ++nt2) {
        const int d = nt2*16 + lc;
        AOb[((size_t)(b*HN + row))*HC + h*HD + d] = f2bf(oacc[mt][nt2][r] * rl);
      }
    }
}

// ---------------- launch ----------------
extern "C" void kernel_launch(void* const* d_in, const int* in_sizes, int n_in,
                              void* d_out, int out_size, void* d_ws, size_t ws_size,
                              hipStream_t stream) {
  const float* x     = (const float*)d_in[0];
  const float* wqkv  = (const float*)d_in[1];
  const float* wproj = (const float*)d_in[2];
  float* out = (float*)d_out;

  char* ws = (char*)d_ws;
  size_t off = 0;
  auto alloc = [&](size_t bytes) -> void* {
    void* p = ws + off; off += (bytes + 255) & ~(size_t)255; return p;
  };
  short* xb     = (short*)alloc((size_t)ROWS*HC*2);        // 12.6 MB
  short* wqkvb  = (short*)alloc((size_t)3*HC*HC*2);        //  3.5 MB
  short* wprojb = (short*)alloc((size_t)HC*HC*2);          //  1.2 MB
  short* vb     = (short*)alloc((size_t)ROWS*HC*2);        // 12.6 MB
  short* Qb     = (short*)alloc((size_t)BH*HN*HD*2);       // 12.6 MB
  short* Kb     = (short*)alloc((size_t)BH*HN*HD*2);       // 12.6 MB
  short* Vtb    = (short*)alloc((size_t)BH*HD*HN*2);       // 12.6 MB
  short* AOb    = (short*)alloc((size_t)ROWS*HC*2);        // 12.6 MB  (~80 MB total)

  { const int n0 = ROWS*HC/4, n1 = 3*HC*HC/4, n2 = HC*HC/4;
    const int tot = n0 + n1 + n2;
    cvt3_kernel<<<(tot + 255)/256, 256, 0, stream>>>(x, xb, n0, wqkv, wqkvb, n1,
                                                     wproj, wprojb, n2); }

  // 576 = 32 m-blocks x 18 n-blocks, XCD-swizzled inside the kernel
  gemm_qkv<<<dim3(576), 512, 0, stream>>>(xb, wqkvb, Qb, Kb, vb);
  vtrans_kernel<<<BH*8, 256, 0, stream>>>(vb, Vtb);
  attn_kernel<<<BH*8, 256, 0, stream>>>(Qb, Kb, Vtb, AOb);
  gemm_bt_f32<<<dim3(HC/128, ROWS/128), 256, 0, stream>>>(AOb, wprojb, out,
                                                          ROWS, HC, HC);
}

// Round 3
// 185.104 us; speedup vs baseline: 1.1051x; 1.0824x over previous
//
#include <hip/hip_runtime.h>
#include <stdint.h>
#include <stddef.h>

// Problem constants
#define HB 8
#define HN 1024
#define HC 768
#define HH 12
#define HD 64
#define ROWS (HB*HN)      // 8192
#define BH (HB*HH)        // 96

using s16x4  = __attribute__((ext_vector_type(4))) short;
using bf16x8 = __attribute__((ext_vector_type(8))) short;
using f32x4  = __attribute__((ext_vector_type(4))) float;

__device__ __forceinline__ short f2bf(float f) {
  union { float f; uint32_t u; } c; c.f = f;
  uint32_t u = c.u;
  uint32_t r = (u + 0x7fffu + ((u >> 16) & 1u)) >> 16;   // RNE
  return (short)r;
}
__device__ __forceinline__ float bf2f(short s) {
  union { uint32_t u; float f; } c; c.u = ((uint32_t)(uint16_t)s) << 16;
  return c.f;
}
// pack two f32 -> {bf16(a) | bf16(b)<<16} with RNE, via v_perm_b32
__device__ __forceinline__ uint32_t pack_bf16_rne(float a, float b) {
  union { float f; uint32_t u; } ca, cb; ca.f = a; cb.f = b;
  uint32_t ra = ca.u + 0x7fffu + ((ca.u >> 16) & 1u);
  uint32_t rb = cb.u + 0x7fffu + ((cb.u >> 16) & 1u);
  return __builtin_amdgcn_perm(rb, ra, 0x07060302);  // {rb[31:16], ra[31:16]}
}
__device__ __forceinline__ float fast_exp2(float x) {
#if __has_builtin(__builtin_amdgcn_exp2f)
  return __builtin_amdgcn_exp2f(x);
#else
  return exp2f(x);
#endif
}
__device__ __forceinline__ f32x4 mfma16(bf16x8 a, bf16x8 b, f32x4 c) {
  return __builtin_amdgcn_mfma_f32_16x16x32_bf16(a, b, c, 0, 0, 0);
}
// async global->LDS, 16B per lane. LDS dest MUST be wave-uniform base + lane*16.
__device__ __forceinline__ void gll16(const void* g, void* l) {
  __builtin_amdgcn_global_load_lds((const __attribute__((address_space(1))) void*)g,
                                   (__attribute__((address_space(3))) void*)l,
                                   16, 0, 0);
}

// ---------------- fused f32 -> bf16 convert for all 3 inputs ----------------
__global__ void cvt3_kernel(const float* __restrict__ x,  short* __restrict__ xb,  int n0,
                            const float* __restrict__ wq, short* __restrict__ wqb, int n1,
                            const float* __restrict__ wp, short* __restrict__ wpb, int n2) {
  int i = blockIdx.x * 256 + threadIdx.x;        // index in float4 units
  const float* in; short* out;
  if (i < n0)            { in = x;  out = xb;  }
  else if (i < n0 + n1)  { i -= n0; in = wq; out = wqb; }
  else if (i < n0 + n1 + n2) { i -= n0 + n1; in = wp; out = wpb; }
  else return;
  float4 v = ((const float4*)in)[i];
  s16x4 o;
  o.x = f2bf(v.x); o.y = f2bf(v.y); o.z = f2bf(v.z); o.w = f2bf(v.w);
  ((s16x4*)out)[i] = o;
}

__device__ __forceinline__ void store_c(float* p, float v) { *p = v; }
__device__ __forceinline__ void store_c(short* p, float v) { *p = f2bf(v); }

// ---------------- GEMM 1: qkv = x*Wqkv^T ------------------------------------
// R11 pipeline (proven 53 us): BM=256 BN=128 BK=32, 512 thr (8 waves, 4Mx2N),
// 3 LDS slots, 2-deep staging, one barrier + one vmcnt(3) per K-tile.
// R12: v-epilogue writes Vtb DIRECTLY (key-permuted transpose via LDS reuse),
// eliminating the vtrans kernel and the vb buffer entirely. Values bit-identical
// (old path: f2bf(acc) -> bf2f -> f2bf was idempotent).
template<int VM, bool STG, int SLOT>
__device__ __forceinline__ void qkv_ktile(
    int kt, short* sA, short* sB,
    const short* Ag, const short* Bg,
    int wr, int wc, int quad, int lc,
    int aoff0, int aoff1, int boff0,      // per-thread source offsets (row*HC+swz-col)
    int cA0, int cA1, int cB0,            // per-thread LDS chunk ids
    f32x4 (&acc)[4][4])
{
  // T(kt) landed for THIS wave; barrier makes it true for ALL waves.
  if constexpr (VM == 3) asm volatile("s_waitcnt vmcnt(3)" ::: "memory");
  else                   asm volatile("s_waitcnt vmcnt(0)" ::: "memory");
  __builtin_amdgcn_s_barrier();
  // After the barrier every wave finished iteration kt-1 (incl. its ds_reads
  // of slot (kt-1)%3) -> safe to stage kt+2 into that slot.
  if constexpr (STG) {
    constexpr int DST = (SLOT + 2) % 3;
    const int kcol = (kt + 2) * 32;
    short* dA = sA + DST*8192;
    short* dB = sB + DST*4096;
    gll16(Ag + (size_t)(aoff0 + kcol), (void*)(dA + cA0*8));
    gll16(Ag + (size_t)(aoff1 + kcol), (void*)(dA + cA1*8));
    gll16(Bg + (size_t)(boff0 + kcol), (void*)(dB + cB0*8));
  }
  const short* sa = sA + SLOT*8192;
  const short* sb = sB + SLOT*4096;
  bf16x8 af[4], bfr[4];
#pragma unroll
  for (int mt = 0; mt < 4; ++mt) {
    const int rA = wr*64 + mt*16 + lc;
    af[mt] = *(const bf16x8*)(sa + rA*32 + (quad ^ ((rA >> 1) & 3))*8);
  }
#pragma unroll
  for (int nt = 0; nt < 4; ++nt) {
    const int rB = wc*64 + nt*16 + lc;
    bfr[nt] = *(const bf16x8*)(sb + rB*32 + (quad ^ ((rB >> 1) & 3))*8);
  }
  __builtin_amdgcn_s_setprio(1);
#pragma unroll
  for (int mt = 0; mt < 4; ++mt)
#pragma unroll
    for (int nt = 0; nt < 4; ++nt)
      acc[mt][nt] = mfma16(af[mt], bfr[nt], acc[mt][nt]);
  __builtin_amdgcn_s_setprio(0);
}

__global__ __launch_bounds__(512, 4) void gemm_qkv(const short* __restrict__ A,
                                                   const short* __restrict__ Bw,
                                                   short* __restrict__ Qb,
                                                   short* __restrict__ Kb,
                                                   short* __restrict__ Vtb) {
  __shared__ short SMEM[3*256*32 + 3*128*32];   // 72 KiB, reused by v-epilogue
  short* As = SMEM;                 // 3 x [256][32]
  short* Bs = SMEM + 3*256*32;      // 3 x [128][32]
  // XCD-bijective swizzle: 576 wgs = 8 XCDs x 72 (4 m-panels x 18 n) each.
  const int wg = blockIdx.x;
  const int swz = (wg & 7)*72 + (wg >> 3);
  const int by = swz / 18, bx = swz % 18;
  const int m0 = by*256, n0 = bx*128;
  const int tid = threadIdx.x;
  const int lane = tid & 63, w = tid >> 6, quad = lane >> 4, lc = lane & 15;
  const int wr = w >> 1, wc = w & 1;           // 4 x 2 wave grid
  // staging: A tile 256x32 = 1024 16B-chunks (2/thread); B 128x32 = 512 (1/thread)
  // chunk c: r = c>>2, cb = c&3; source col pre-swizzled cb ^ ((r>>1)&3)
  const int cA0 = tid,        rA0 = cA0 >> 2, sbA0 = ((cA0 & 3) ^ ((rA0 >> 1) & 3))*8;
  const int cA1 = 512 + tid,  rA1 = cA1 >> 2, sbA1 = ((cA1 & 3) ^ ((rA1 >> 1) & 3))*8;
  const int cB0 = tid,        rB0 = cB0 >> 2, sbB0 = ((cB0 & 3) ^ ((rB0 >> 1) & 3))*8;
  const int aoff0 = rA0*HC + sbA0;
  const int aoff1 = rA1*HC + sbA1;
  const int boff0 = rB0*HC + sbB0;
  const short* Ag = A  + (size_t)m0*HC;
  const short* Bg = Bw + (size_t)n0*HC;
  f32x4 acc[4][4] = {};

  // prologue: stage K-tiles 0 and 1 (FIFO order: T0's 3 loads, then T1's 3)
#pragma unroll
  for (int pk = 0; pk < 2; ++pk) {
    gll16(Ag + (size_t)(aoff0 + pk*32), (void*)(As + pk*8192 + cA0*8));
    gll16(Ag + (size_t)(aoff1 + pk*32), (void*)(As + pk*8192 + cA1*8));
    gll16(Bg + (size_t)(boff0 + pk*32), (void*)(Bs + pk*4096 + cB0*8));
  }

  // main loop: 24 K-tiles, unrolled by 3 so the slot index is compile-time
#pragma unroll 1
  for (int kt = 0; kt < 21; kt += 3) {
    qkv_ktile<3,true,0>(kt,   As, Bs, Ag, Bg, wr, wc, quad, lc,
                        aoff0, aoff1, boff0, cA0, cA1, cB0, acc);
    qkv_ktile<3,true,1>(kt+1, As, Bs, Ag, Bg, wr, wc, quad, lc,
                        aoff0, aoff1, boff0, cA0, cA1, cB0, acc);
    qkv_ktile<3,true,2>(kt+2, As, Bs, Ag, Bg, wr, wc, quad, lc,
                        aoff0, aoff1, boff0, cA0, cA1, cB0, acc);
  }
  qkv_ktile<3,true ,0>(21, As, Bs, Ag, Bg, wr, wc, quad, lc,
                       aoff0, aoff1, boff0, cA0, cA1, cB0, acc);   // stages T23
  qkv_ktile<3,false,1>(22, As, Bs, Ag, Bg, wr, wc, quad, lc,
                       aoff0, aoff1, boff0, cA0, cA1, cB0, acc);
  qkv_ktile<0,false,2>(23, As, Bs, Ag, Bg, wr, wc, quad, lc,
                       aoff0, aoff1, boff0, cA0, cA1, cB0, acc);

  // epilogue (C/D: col=nt*16+lc, row=quad*4+r); per-wave 64-col group = 1 head
  const int cg = n0 + wc*64;
  const int t = cg / HC;                // 0=q, 1=k, 2=v (block-uniform: n0 % 128 == 0)
  const int h = (cg % HC) / HD;
  if (t < 2) {
    short* outp = (t == 0) ? Qb : Kb;
    const float sc = (t == 0) ? 0.125f : 1.0f;   // SCALE = 64^-0.5 for q
#pragma unroll
    for (int i = 0; i < 4; ++i)
#pragma unroll
      for (int r = 0; r < 4; ++r) {
        float s1 = (acc[i][0][r] + acc[i][1][r]) + (acc[i][2][r] + acc[i][3][r]);
        float s2 = acc[i][0][r]*acc[i][0][r];
        s2 = __builtin_fmaf(acc[i][1][r], acc[i][1][r], s2);
        s2 = __builtin_fmaf(acc[i][2][r], acc[i][2][r], s2);
        s2 = __builtin_fmaf(acc[i][3][r], acc[i][3][r], s2);
#pragma unroll
        for (int off = 1; off < 16; off <<= 1) {
          s1 += __shfl_xor(s1, off);
          s2 += __shfl_xor(s2, off);
        }
        const float mean = s1 * (1.0f/64.0f);
        const float var  = s2 * (1.0f/64.0f) - mean*mean;
        const float inv  = rsqrtf(var + 1e-5f) * sc;
        const int row = m0 + wr*64 + i*16 + quad*4 + r;
        const int b = row >> 10, n_in = row & 1023;
        short* rowp = outp + ((size_t)(b*HH + h)*HN + n_in)*HD;
#pragma unroll
        for (int nt = 0; nt < 4; ++nt)
          rowp[nt*16 + lc] = f2bf((acc[i][nt][r] - mean) * inv);
      }
  } else {
    // fused V-transpose: acc -> LDS (key-permuted, stride 268) -> Vtb.
    // Storage col c holds key k: c(k) = ((k&15)<<2)|(k>>4); inverse of
    // vtrans's perm(c) = (c&3)*16 + (c>>2)  [perm(c(k)) == k].
    short* vs = SMEM;                 // [2][64][268] = 34304 shorts <= 36864
    __syncthreads();                  // main-loop LDS fully consumed by all waves
    const int hd = wc;                // wave's head slot (0/1)
#pragma unroll
    for (int i = 0; i < 4; ++i)
#pragma unroll
      for (int nt = 0; nt < 4; ++nt)
#pragma unroll
        for (int r = 0; r < 4; ++r) {
          const int dd = nt*16 + lc;
          const int k  = i*16 + quad*4 + r;            // row within 64-group
          const int c  = ((k & 15) << 2) | (k >> 4);   // permuted col
          vs[(hd*64 + dd)*268 + wr*64 + c] = f2bf(acc[i][nt][r]);
        }
    __syncthreads();
    const int b = m0 >> 10, m0g = m0 & 1023;
#pragma unroll
    for (int it = 0; it < 8; ++it) {
      const int idx = it*512 + tid;        // [0,4096)
      const int h2 = idx >> 11;            // head slot 0/1
      const int rem = idx & 2047;
      const int dd = rem >> 5, c8 = rem & 31;
      const int habs = ((n0 + h2*64) - 1536) >> 6;     // absolute head
      const short* src = vs + (h2*64 + dd)*268 + c8*8; // 8B-aligned
      s16x4 lo = *(const s16x4*)(src);
      s16x4 hi = *(const s16x4*)(src + 4);
      bf16x8 vvv;
      vvv[0]=lo[0]; vvv[1]=lo[1]; vvv[2]=lo[2]; vvv[3]=lo[3];
      vvv[4]=hi[0]; vvv[5]=hi[1]; vvv[6]=hi[2]; vvv[7]=hi[3];
      *(bf16x8*)(Vtb + ((size_t)((b*HH + habs)*HD + dd))*HN + m0g + c8*8) = vvv;
    }
  }
}

// ---------------- GEMM 2: out = AO * Wproj^T (f32 out) ----------------------
__global__ __launch_bounds__(256) void gemm_bt_f32(const short* __restrict__ A,
                                                   const short* __restrict__ Bw,
                                                   float* __restrict__ C,
                                                   int M, int N, int K) {
  __shared__ short As[128*64];
  __shared__ short Bs[128*64];
  const int m0 = blockIdx.y * 128, n0 = blockIdx.x * 128;
  const int tid = threadIdx.x;
  const int lane = tid & 63, w = tid >> 6, quad = lane >> 4, lc = lane & 15;
  const int wr = w >> 1, wc = w & 1;
  f32x4 acc[4][4] = {};
  for (int kt = 0; kt < K; kt += 64) {
#pragma unroll
    for (int i = 0; i < 4; ++i) {
      const int chunk = i*256 + tid;
      const int r = chunk >> 3, cb = chunk & 7;
      const int cbs = cb ^ (r & 7);
      gll16(A  + (size_t)(m0 + r)*K + kt + cbs*8, (void*)(As + (size_t)chunk*8));
      gll16(Bw + (size_t)(n0 + r)*K + kt + cbs*8, (void*)(Bs + (size_t)chunk*8));
    }
    __syncthreads();
#pragma unroll
    for (int kk = 0; kk < 2; ++kk) {
      bf16x8 af[4], bfr[4];
      const int kb = kk*4 + quad;
#pragma unroll
      for (int mt = 0; mt < 4; ++mt)
        af[mt] = *(const bf16x8*)(As + (wr*64 + mt*16 + lc)*64 + (kb ^ (lc & 7))*8);
#pragma unroll
      for (int nt = 0; nt < 4; ++nt)
        bfr[nt] = *(const bf16x8*)(Bs + (wc*64 + nt*16 + lc)*64 + (kb ^ (lc & 7))*8);
#pragma unroll
      for (int mt = 0; mt < 4; ++mt)
#pragma unroll
        for (int nt = 0; nt < 4; ++nt)
          acc[mt][nt] = mfma16(af[mt], bfr[nt], acc[mt][nt]);
    }
    __syncthreads();
  }
#pragma unroll
  for (int mt = 0; mt < 4; ++mt)
#pragma unroll
    for (int nt = 0; nt < 4; ++nt)
#pragma unroll
      for (int r = 0; r < 4; ++r) {
        const int row = m0 + wr*64 + mt*16 + quad*4 + r;
        const int col = n0 + wc*64 + nt*16 + lc;
        store_c(C + (size_t)row*N + col, acc[mt][nt][r]);
      }
}

// ---------------- flash attention: 128 q-rows/block, 64-key chunks ----------
// R9: each wave owns 32 q-rows (2 m-tiles) -> per chunk 32 MFMA + 32 exp
// against the SAME staging cost as R6's 16+16 -> barriers per unit work halve,
// K/V global traffic halves. Grid 768 blocks = 3/CU; LDS 36864 B.
__global__ __launch_bounds__(256, 3) void attn_kernel(const short* __restrict__ Qb,
                                                      const short* __restrict__ Kb,
                                                      const short* __restrict__ Vtb,
                                                      short* __restrict__ AOb) {
  const int blk = blockIdx.x;
  const int qt = blk & 7, bh = blk >> 3;
  const int b = bh / HH, h = bh % HH;
  const int tid = threadIdx.x, w = tid >> 6, lane = tid & 63;
  const int quad = lane >> 4, lc = lane & 15;

  __shared__ short Ks [64][72];      // K chunk: row=key(natural), padded
  __shared__ short Vts[64][72];      // V chunk: row=d, cols=64 keys permuted
  __shared__ short Ps [4][32][72];   // per-wave P stash (32 q-rows), permuted keys

  // Q A-fragments: A[m=lane&15][k=quad*8+j]; wave rows qt*128 + w*32 + mt*16
  bf16x8 aq[2][2];
#pragma unroll
  for (int mt = 0; mt < 2; ++mt) {
    const int mrow = qt*128 + w*32 + mt*16 + lc;
    aq[mt][0] = *(const bf16x8*)(Qb + ((size_t)bh*HN + mrow)*HD + quad*8);
    aq[mt][1] = *(const bf16x8*)(Qb + ((size_t)bh*HN + mrow)*HD + 32 + quad*8);
  }

  const short* kbh = Kb  + (size_t)bh*HN*HD;
  const short* vbh = Vtb + (size_t)bh*HD*HN;

  f32x4 oacc[2][4] = {};
  float l_i[2][4] = {};

  // staging regs: c = i*256+tid in [0,512); row=c>>3 in [0,64), cb=c&7
  bf16x8 gk[2], gv[2];
#pragma unroll
  for (int i = 0; i < 2; ++i) {
    const int c = i*256 + tid;
    gk[i] = *(const bf16x8*)(kbh + (size_t)(c >> 3)*HD + (c & 7)*8);
    gv[i] = *(const bf16x8*)(vbh + (size_t)(c >> 3)*HN + (c & 7)*8);
  }
#pragma unroll
  for (int i = 0; i < 2; ++i) {
    const int c = i*256 + tid;
    *(bf16x8*)(&Ks [c >> 3][(c & 7)*8]) = gk[i];
    *(bf16x8*)(&Vts[c >> 3][(c & 7)*8]) = gv[i];
  }
  __syncthreads();

  const float LOG2E = 1.44269504f;
  const float MB2   = 8.0f * 1.44269504f;   // fixed max * log2(e)

  for (int ck = 0; ck < 16; ++ck) {
    // prefetch chunk ck+1 into registers (overlaps with compute below)
    if (ck < 15) {
      const int nn0 = (ck + 1)*64;
#pragma unroll
      for (int i = 0; i < 2; ++i) {
        const int c = i*256 + tid;
        gk[i] = *(const bf16x8*)(kbh + (size_t)(nn0 + (c >> 3))*HD + (c & 7)*8);
        gv[i] = *(const bf16x8*)(vbh + (size_t)(c >> 3)*HN + nn0 + (c & 7)*8);
      }
    }

    // S = Q K^T : 16 MFMAs (2 m-tiles x 2 kk x 4 nt)
    f32x4 sacc[2][4] = {};
#pragma unroll
    for (int kk = 0; kk < 2; ++kk)
#pragma unroll
      for (int nt = 0; nt < 4; ++nt) {
        bf16x8 bk = *(const bf16x8*)(&Ks[nt*16 + lc][kk*32 + quad*8]);
#pragma unroll
        for (int mt = 0; mt < 2; ++mt)
          sacc[mt][nt] = mfma16(aq[mt][kk], bk, sacc[mt][nt]);
      }

    // fixed-max softmax + P stash (C->A relayout, ds_write_b64 per row)
#pragma unroll
    for (int mt = 0; mt < 2; ++mt)
#pragma unroll
      for (int r = 0; r < 4; ++r) {
        float ps[4];
#pragma unroll
        for (int nt = 0; nt < 4; ++nt) {
          ps[nt] = fast_exp2(__builtin_fmaf(sacc[mt][nt][r], LOG2E, -MB2));
          sacc[mt][nt][r] = ps[nt];
        }
        l_i[mt][r] += (ps[0] + ps[1]) + (ps[2] + ps[3]);
        uint2 pk;
        pk.x = pack_bf16_rne(ps[0], ps[1]);
        pk.y = pack_bf16_rne(ps[2], ps[3]);
        *(uint2*)(&Ps[w][mt*16 + quad*4 + r][lc*4]) = pk;
      }

    // O += P V : 16 MFMAs (A from Ps, B from Vts; both in permuted key space)
#pragma unroll
    for (int kk = 0; kk < 2; ++kk) {
      bf16x8 ap[2];
#pragma unroll
      for (int mt = 0; mt < 2; ++mt)
        ap[mt] = *(const bf16x8*)(&Ps[w][mt*16 + lc][kk*32 + quad*8]);
#pragma unroll
      for (int nt2 = 0; nt2 < 4; ++nt2) {
        bf16x8 bv = *(const bf16x8*)(&Vts[nt2*16 + lc][kk*32 + quad*8]);
#pragma unroll
        for (int mt = 0; mt < 2; ++mt)
          oacc[mt][nt2] = mfma16(ap[mt], bv, oacc[mt][nt2]);
      }
    }

    if (ck < 15) {
      __syncthreads();   // all waves done reading Ks/Vts
#pragma unroll
      for (int i = 0; i < 2; ++i) {
        const int c = i*256 + tid;
        *(bf16x8*)(&Ks [c >> 3][(c & 7)*8]) = gk[i];
        *(bf16x8*)(&Vts[c >> 3][(c & 7)*8]) = gv[i];
      }
      __syncthreads();
    }
  }

  // epilogue: reduce l across the 16 lanes of each quad, then scale & store
#pragma unroll
  for (int mt = 0; mt < 2; ++mt)
#pragma unroll
    for (int r = 0; r < 4; ++r) {
      float l = l_i[mt][r];
#pragma unroll
      for (int off = 1; off < 16; off <<= 1) l += __shfl_xor(l, off);
      const float rl = 1.0f / l;
      const int row = qt*128 + w*32 + mt*16 + quad*4 + r;
#pragma unroll
      for (int nt2 = 0; nt2 < 4; ++nt2) {
        const int d = nt2*16 + lc;
        AOb[((size_t)(b*HN + row))*HC + h*HD + d] = f2bf(oacc[mt][nt2][r] * rl);
      }
    }
}

// ---------------- launch ----------------
extern "C" void kernel_launch(void* const* d_in, const int* in_sizes, int n_in,
                              void* d_out, int out_size, void* d_ws, size_t ws_size,
                              hipStream_t stream) {
  const float* x     = (const float*)d_in[0];
  const float* wqkv  = (const float*)d_in[1];
  const float* wproj = (const float*)d_in[2];
  float* out = (float*)d_out;

  char* ws = (char*)d_ws;
  size_t off = 0;
  auto alloc = [&](size_t bytes) -> void* {
    void* p = ws + off; off += (bytes + 255) & ~(size_t)255; return p;
  };
  short* xb     = (short*)alloc((size_t)ROWS*HC*2);        // 12.6 MB
  short* wqkvb  = (short*)alloc((size_t)3*HC*HC*2);        //  3.5 MB
  short* wprojb = (short*)alloc((size_t)HC*HC*2);          //  1.2 MB
  short* Qb     = (short*)alloc((size_t)BH*HN*HD*2);       // 12.6 MB
  short* Kb     = (short*)alloc((size_t)BH*HN*HD*2);       // 12.6 MB
  short* Vtb    = (short*)alloc((size_t)BH*HD*HN*2);       // 12.6 MB
  short* AOb    = (short*)alloc((size_t)ROWS*HC*2);        // 12.6 MB  (~68 MB total)

  { const int n0 = ROWS*HC/4, n1 = 3*HC*HC/4, n2 = HC*HC/4;
    const int tot = n0 + n1 + n2;
    cvt3_kernel<<<(tot + 255)/256, 256, 0, stream>>>(x, xb, n0, wqkv, wqkvb, n1,
                                                     wproj, wprojb, n2); }

  // 576 = 32 m-blocks x 18 n-blocks, XCD-swizzled inside the kernel
  gemm_qkv<<<dim3(576), 512, 0, stream>>>(xb, wqkvb, Qb, Kb, Vtb);
  attn_kernel<<<BH*8, 256, 0, stream>>>(Qb, Kb, Vtb, AOb);
  gemm_bt_f32<<<dim3(HC/128, ROWS/128), 256, 0, stream>>>(AOb, wprojb, out,
                                                          ROWS, HC, HC);
}

// Round 5
// 182.585 us; speedup vs baseline: 1.1203x; 1.0138x over previous
//
#include <hip/hip_runtime.h>
#include <stdint.h>
#include <stddef.h>

// Problem constants
#define HB 8
#define HN 1024
#define HC 768
#define HH 12
#define HD 64
#define ROWS (HB*HN)      // 8192
#define BH (HB*HH)        // 96

using s16x4  = __attribute__((ext_vector_type(4))) short;
using bf16x8 = __attribute__((ext_vector_type(8))) short;
using f32x4  = __attribute__((ext_vector_type(4))) float;

__device__ __forceinline__ short f2bf(float f) {
  union { float f; uint32_t u; } c; c.f = f;
  uint32_t u = c.u;
  uint32_t r = (u + 0x7fffu + ((u >> 16) & 1u)) >> 16;   // RNE
  return (short)r;
}
__device__ __forceinline__ float bf2f(short s) {
  union { uint32_t u; float f; } c; c.u = ((uint32_t)(uint16_t)s) << 16;
  return c.f;
}
// pack two f32 -> {bf16(a) | bf16(b)<<16} with RNE, via v_perm_b32
__device__ __forceinline__ uint32_t pack_bf16_rne(float a, float b) {
  union { float f; uint32_t u; } ca, cb; ca.f = a; cb.f = b;
  uint32_t ra = ca.u + 0x7fffu + ((ca.u >> 16) & 1u);
  uint32_t rb = cb.u + 0x7fffu + ((cb.u >> 16) & 1u);
  return __builtin_amdgcn_perm(rb, ra, 0x07060302);  // {rb[31:16], ra[31:16]}
}
__device__ __forceinline__ float fast_exp2(float x) {
#if __has_builtin(__builtin_amdgcn_exp2f)
  return __builtin_amdgcn_exp2f(x);
#else
  return exp2f(x);
#endif
}
__device__ __forceinline__ f32x4 mfma16(bf16x8 a, bf16x8 b, f32x4 c) {
  return __builtin_amdgcn_mfma_f32_16x16x32_bf16(a, b, c, 0, 0, 0);
}
// async global->LDS, 16B per lane. LDS dest MUST be wave-uniform base + lane*16.
__device__ __forceinline__ void gll16(const void* g, void* l) {
  __builtin_amdgcn_global_load_lds((const __attribute__((address_space(1))) void*)g,
                                   (__attribute__((address_space(3))) void*)l,
                                   16, 0, 0);
}

// ---------------- fused f32 -> bf16 convert for all 3 inputs ----------------
__global__ void cvt3_kernel(const float* __restrict__ x,  short* __restrict__ xb,  int n0,
                            const float* __restrict__ wq, short* __restrict__ wqb, int n1,
                            const float* __restrict__ wp, short* __restrict__ wpb, int n2) {
  int i = blockIdx.x * 256 + threadIdx.x;        // index in float4 units
  const float* in; short* out;
  if (i < n0)            { in = x;  out = xb;  }
  else if (i < n0 + n1)  { i -= n0; in = wq; out = wqb; }
  else if (i < n0 + n1 + n2) { i -= n0 + n1; in = wp; out = wpb; }
  else return;
  float4 v = ((const float4*)in)[i];
  s16x4 o;
  o.x = f2bf(v.x); o.y = f2bf(v.y); o.z = f2bf(v.z); o.w = f2bf(v.w);
  ((s16x4*)out)[i] = o;
}

__device__ __forceinline__ void store_c(float* p, float v) { *p = v; }
__device__ __forceinline__ void store_c(short* p, float v) { *p = f2bf(v); }

// ---------------- GEMM 1: qkv = x*Wqkv^T ------------------------------------
// R11 pipeline (proven 53 us): BM=256 BN=128 BK=32, 512 thr (8 waves, 4Mx2N),
// 3 LDS slots, 2-deep staging, one barrier + one vmcnt(3) per K-tile.
// R12: v-epilogue writes Vtb DIRECTLY (key-permuted transpose via LDS reuse),
// eliminating the vtrans kernel and the vb buffer entirely. Values bit-identical
// (old path: f2bf(acc) -> bf2f -> f2bf was idempotent).
template<int VM, bool STG, int SLOT>
__device__ __forceinline__ void qkv_ktile(
    int kt, short* sA, short* sB,
    const short* Ag, const short* Bg,
    int wr, int wc, int quad, int lc,
    int aoff0, int aoff1, int boff0,      // per-thread source offsets (row*HC+swz-col)
    int cA0, int cA1, int cB0,            // per-thread LDS chunk ids
    f32x4 (&acc)[4][4])
{
  // T(kt) landed for THIS wave; barrier makes it true for ALL waves.
  if constexpr (VM == 3) asm volatile("s_waitcnt vmcnt(3)" ::: "memory");
  else                   asm volatile("s_waitcnt vmcnt(0)" ::: "memory");
  __builtin_amdgcn_s_barrier();
  // After the barrier every wave finished iteration kt-1 (incl. its ds_reads
  // of slot (kt-1)%3) -> safe to stage kt+2 into that slot.
  if constexpr (STG) {
    constexpr int DST = (SLOT + 2) % 3;
    const int kcol = (kt + 2) * 32;
    short* dA = sA + DST*8192;
    short* dB = sB + DST*4096;
    gll16(Ag + (size_t)(aoff0 + kcol), (void*)(dA + cA0*8));
    gll16(Ag + (size_t)(aoff1 + kcol), (void*)(dA + cA1*8));
    gll16(Bg + (size_t)(boff0 + kcol), (void*)(dB + cB0*8));
  }
  const short* sa = sA + SLOT*8192;
  const short* sb = sB + SLOT*4096;
  bf16x8 af[4], bfr[4];
#pragma unroll
  for (int mt = 0; mt < 4; ++mt) {
    const int rA = wr*64 + mt*16 + lc;
    af[mt] = *(const bf16x8*)(sa + rA*32 + (quad ^ ((rA >> 1) & 3))*8);
  }
#pragma unroll
  for (int nt = 0; nt < 4; ++nt) {
    const int rB = wc*64 + nt*16 + lc;
    bfr[nt] = *(const bf16x8*)(sb + rB*32 + (quad ^ ((rB >> 1) & 3))*8);
  }
  __builtin_amdgcn_s_setprio(1);
#pragma unroll
  for (int mt = 0; mt < 4; ++mt)
#pragma unroll
    for (int nt = 0; nt < 4; ++nt)
      acc[mt][nt] = mfma16(af[mt], bfr[nt], acc[mt][nt]);
  __builtin_amdgcn_s_setprio(0);
}

__global__ __launch_bounds__(512, 4) void gemm_qkv(const short* __restrict__ A,
                                                   const short* __restrict__ Bw,
                                                   short* __restrict__ Qb,
                                                   short* __restrict__ Kb,
                                                   short* __restrict__ Vtb) {
  __shared__ short SMEM[3*256*32 + 3*128*32];   // 72 KiB, reused by v-epilogue
  short* As = SMEM;                 // 3 x [256][32]
  short* Bs = SMEM + 3*256*32;      // 3 x [128][32]
  // XCD-bijective swizzle: 576 wgs = 8 XCDs x 72 (4 m-panels x 18 n) each.
  const int wg = blockIdx.x;
  const int swz = (wg & 7)*72 + (wg >> 3);
  const int by = swz / 18, bx = swz % 18;
  const int m0 = by*256, n0 = bx*128;
  const int tid = threadIdx.x;
  const int lane = tid & 63, w = tid >> 6, quad = lane >> 4, lc = lane & 15;
  const int wr = w >> 1, wc = w & 1;           // 4 x 2 wave grid
  // staging: A tile 256x32 = 1024 16B-chunks (2/thread); B 128x32 = 512 (1/thread)
  // chunk c: r = c>>2, cb = c&3; source col pre-swizzled cb ^ ((r>>1)&3)
  const int cA0 = tid,        rA0 = cA0 >> 2, sbA0 = ((cA0 & 3) ^ ((rA0 >> 1) & 3))*8;
  const int cA1 = 512 + tid,  rA1 = cA1 >> 2, sbA1 = ((cA1 & 3) ^ ((rA1 >> 1) & 3))*8;
  const int cB0 = tid,        rB0 = cB0 >> 2, sbB0 = ((cB0 & 3) ^ ((rB0 >> 1) & 3))*8;
  const int aoff0 = rA0*HC + sbA0;
  const int aoff1 = rA1*HC + sbA1;
  const int boff0 = rB0*HC + sbB0;
  const short* Ag = A  + (size_t)m0*HC;
  const short* Bg = Bw + (size_t)n0*HC;
  f32x4 acc[4][4] = {};

  // prologue: stage K-tiles 0 and 1 (FIFO order: T0's 3 loads, then T1's 3)
#pragma unroll
  for (int pk = 0; pk < 2; ++pk) {
    gll16(Ag + (size_t)(aoff0 + pk*32), (void*)(As + pk*8192 + cA0*8));
    gll16(Ag + (size_t)(aoff1 + pk*32), (void*)(As + pk*8192 + cA1*8));
    gll16(Bg + (size_t)(boff0 + pk*32), (void*)(Bs + pk*4096 + cB0*8));
  }

  // main loop: 24 K-tiles, unrolled by 3 so the slot index is compile-time
#pragma unroll 1
  for (int kt = 0; kt < 21; kt += 3) {
    qkv_ktile<3,true,0>(kt,   As, Bs, Ag, Bg, wr, wc, quad, lc,
                        aoff0, aoff1, boff0, cA0, cA1, cB0, acc);
    qkv_ktile<3,true,1>(kt+1, As, Bs, Ag, Bg, wr, wc, quad, lc,
                        aoff0, aoff1, boff0, cA0, cA1, cB0, acc);
    qkv_ktile<3,true,2>(kt+2, As, Bs, Ag, Bg, wr, wc, quad, lc,
                        aoff0, aoff1, boff0, cA0, cA1, cB0, acc);
  }
  qkv_ktile<3,true ,0>(21, As, Bs, Ag, Bg, wr, wc, quad, lc,
                       aoff0, aoff1, boff0, cA0, cA1, cB0, acc);   // stages T23
  qkv_ktile<3,false,1>(22, As, Bs, Ag, Bg, wr, wc, quad, lc,
                       aoff0, aoff1, boff0, cA0, cA1, cB0, acc);
  qkv_ktile<0,false,2>(23, As, Bs, Ag, Bg, wr, wc, quad, lc,
                       aoff0, aoff1, boff0, cA0, cA1, cB0, acc);

  // epilogue (C/D: col=nt*16+lc, row=quad*4+r); per-wave 64-col group = 1 head
  const int cg = n0 + wc*64;
  const int t = cg / HC;                // 0=q, 1=k, 2=v (block-uniform: n0 % 128 == 0)
  const int h = (cg % HC) / HD;
  if (t < 2) {
    short* outp = (t == 0) ? Qb : Kb;
    const float sc = (t == 0) ? 0.125f : 1.0f;   // SCALE = 64^-0.5 for q
#pragma unroll
    for (int i = 0; i < 4; ++i)
#pragma unroll
      for (int r = 0; r < 4; ++r) {
        float s1 = (acc[i][0][r] + acc[i][1][r]) + (acc[i][2][r] + acc[i][3][r]);
        float s2 = acc[i][0][r]*acc[i][0][r];
        s2 = __builtin_fmaf(acc[i][1][r], acc[i][1][r], s2);
        s2 = __builtin_fmaf(acc[i][2][r], acc[i][2][r], s2);
        s2 = __builtin_fmaf(acc[i][3][r], acc[i][3][r], s2);
#pragma unroll
        for (int off = 1; off < 16; off <<= 1) {
          s1 += __shfl_xor(s1, off);
          s2 += __shfl_xor(s2, off);
        }
        const float mean = s1 * (1.0f/64.0f);
        const float var  = s2 * (1.0f/64.0f) - mean*mean;
        const float inv  = rsqrtf(var + 1e-5f) * sc;
        const int row = m0 + wr*64 + i*16 + quad*4 + r;
        const int b = row >> 10, n_in = row & 1023;
        short* rowp = outp + ((size_t)(b*HH + h)*HN + n_in)*HD;
#pragma unroll
        for (int nt = 0; nt < 4; ++nt)
          rowp[nt*16 + lc] = f2bf((acc[i][nt][r] - mean) * inv);
      }
  } else {
    // fused V-transpose: acc -> LDS (key-permuted, stride 268) -> Vtb.
    // Storage col c holds key k: c(k) = ((k&15)<<2)|(k>>4); inverse of
    // vtrans's perm(c) = (c&3)*16 + (c>>2)  [perm(c(k)) == k].
    short* vs = SMEM;                 // [2][64][268] = 34304 shorts <= 36864
    __syncthreads();                  // main-loop LDS fully consumed by all waves
    const int hd = wc;                // wave's head slot (0/1)
#pragma unroll
    for (int i = 0; i < 4; ++i)
#pragma unroll
      for (int nt = 0; nt < 4; ++nt)
#pragma unroll
        for (int r = 0; r < 4; ++r) {
          const int dd = nt*16 + lc;
          const int k  = i*16 + quad*4 + r;            // row within 64-group
          const int c  = ((k & 15) << 2) | (k >> 4);   // permuted col
          vs[(hd*64 + dd)*268 + wr*64 + c] = f2bf(acc[i][nt][r]);
        }
    __syncthreads();
    const int b = m0 >> 10, m0g = m0 & 1023;
#pragma unroll
    for (int it = 0; it < 8; ++it) {
      const int idx = it*512 + tid;        // [0,4096)
      const int h2 = idx >> 11;            // head slot 0/1
      const int rem = idx & 2047;
      const int dd = rem >> 5, c8 = rem & 31;
      const int habs = ((n0 + h2*64) - 1536) >> 6;     // absolute head
      const short* src = vs + (h2*64 + dd)*268 + c8*8; // 8B-aligned
      s16x4 lo = *(const s16x4*)(src);
      s16x4 hi = *(const s16x4*)(src + 4);
      bf16x8 vvv;
      vvv[0]=lo[0]; vvv[1]=lo[1]; vvv[2]=lo[2]; vvv[3]=lo[3];
      vvv[4]=hi[0]; vvv[5]=hi[1]; vvv[6]=hi[2]; vvv[7]=hi[3];
      *(bf16x8*)(Vtb + ((size_t)((b*HH + habs)*HD + dd))*HN + m0g + c8*8) = vvv;
    }
  }
}

// ---------------- GEMM 2: out = AO * Wproj^T (f32 out) ----------------------
__global__ __launch_bounds__(256) void gemm_bt_f32(const short* __restrict__ A,
                                                   const short* __restrict__ Bw,
                                                   float* __restrict__ C,
                                                   int M, int N, int K) {
  __shared__ short As[128*64];
  __shared__ short Bs[128*64];
  const int m0 = blockIdx.y * 128, n0 = blockIdx.x * 128;
  const int tid = threadIdx.x;
  const int lane = tid & 63, w = tid >> 6, quad = lane >> 4, lc = lane & 15;
  const int wr = w >> 1, wc = w & 1;
  f32x4 acc[4][4] = {};
  for (int kt = 0; kt < K; kt += 64) {
#pragma unroll
    for (int i = 0; i < 4; ++i) {
      const int chunk = i*256 + tid;
      const int r = chunk >> 3, cb = chunk & 7;
      const int cbs = cb ^ (r & 7);
      gll16(A  + (size_t)(m0 + r)*K + kt + cbs*8, (void*)(As + (size_t)chunk*8));
      gll16(Bw + (size_t)(n0 + r)*K + kt + cbs*8, (void*)(Bs + (size_t)chunk*8));
    }
    __syncthreads();
#pragma unroll
    for (int kk = 0; kk < 2; ++kk) {
      bf16x8 af[4], bfr[4];
      const int kb = kk*4 + quad;
#pragma unroll
      for (int mt = 0; mt < 4; ++mt)
        af[mt] = *(const bf16x8*)(As + (wr*64 + mt*16 + lc)*64 + (kb ^ (lc & 7))*8);
#pragma unroll
      for (int nt = 0; nt < 4; ++nt)
        bfr[nt] = *(const bf16x8*)(Bs + (wc*64 + nt*16 + lc)*64 + (kb ^ (lc & 7))*8);
#pragma unroll
      for (int mt = 0; mt < 4; ++mt)
#pragma unroll
        for (int nt = 0; nt < 4; ++nt)
          acc[mt][nt] = mfma16(af[mt], bfr[nt], acc[mt][nt]);
    }
    __syncthreads();
  }
#pragma unroll
  for (int mt = 0; mt < 4; ++mt)
#pragma unroll
    for (int nt = 0; nt < 4; ++nt)
#pragma unroll
      for (int r = 0; r < 4; ++r) {
        const int row = m0 + wr*64 + mt*16 + quad*4 + r;
        const int col = n0 + wc*64 + nt*16 + lc;
        store_c(C + (size_t)row*N + col, acc[mt][nt][r]);
      }
}

// ---------------- flash attention: 128 q-rows/block, 64-key chunks ----------
// R9 structure; R13: XCD-grouped block swizzle. Dispatch assigns XCD = raw%8;
// remap so XCD x owns bh in [12x, 12x+12) with all 8 q-tiles of each bh on
// the same XCD -> per-XCD K/V working set 12*256KB = 3MB fits the 4MB L2.
// (was: bh's 8 q-tiles spread over 8 XCDs -> 8x K/V HBM fetch, 104MB measured)
__global__ __launch_bounds__(256, 3) void attn_kernel(const short* __restrict__ Qb,
                                                      const short* __restrict__ Kb,
                                                      const short* __restrict__ Vtb,
                                                      short* __restrict__ AOb) {
  const int raw = blockIdx.x;
  const int blk = (raw & 7)*96 + (raw >> 3);   // bijective on [0,768)
  const int qt = blk & 7, bh = blk >> 3;
  const int b = bh / HH, h = bh % HH;
  const int tid = threadIdx.x, w = tid >> 6, lane = tid & 63;
  const int quad = lane >> 4, lc = lane & 15;

  __shared__ short Ks [64][72];      // K chunk: row=key(natural), padded
  __shared__ short Vts[64][72];      // V chunk: row=d, cols=64 keys permuted
  __shared__ short Ps [4][32][72];   // per-wave P stash (32 q-rows), permuted keys

  // Q A-fragments: A[m=lane&15][k=quad*8+j]; wave rows qt*128 + w*32 + mt*16
  bf16x8 aq[2][2];
#pragma unroll
  for (int mt = 0; mt < 2; ++mt) {
    const int mrow = qt*128 + w*32 + mt*16 + lc;
    aq[mt][0] = *(const bf16x8*)(Qb + ((size_t)bh*HN + mrow)*HD + quad*8);
    aq[mt][1] = *(const bf16x8*)(Qb + ((size_t)bh*HN + mrow)*HD + 32 + quad*8);
  }

  const short* kbh = Kb  + (size_t)bh*HN*HD;
  const short* vbh = Vtb + (size_t)bh*HD*HN;

  f32x4 oacc[2][4] = {};
  float l_i[2][4] = {};

  // staging regs: c = i*256+tid in [0,512); row=c>>3 in [0,64), cb=c&7
  bf16x8 gk[2], gv[2];
#pragma unroll
  for (int i = 0; i < 2; ++i) {
    const int c = i*256 + tid;
    gk[i] = *(const bf16x8*)(kbh + (size_t)(c >> 3)*HD + (c & 7)*8);
    gv[i] = *(const bf16x8*)(vbh + (size_t)(c >> 3)*HN + (c & 7)*8);
  }
#pragma unroll
  for (int i = 0; i < 2; ++i) {
    const int c = i*256 + tid;
    *(bf16x8*)(&Ks [c >> 3][(c & 7)*8]) = gk[i];
    *(bf16x8*)(&Vts[c >> 3][(c & 7)*8]) = gv[i];
  }
  __syncthreads();

  const float LOG2E = 1.44269504f;
  const float MB2   = 8.0f * 1.44269504f;   // fixed max * log2(e)

  for (int ck = 0; ck < 16; ++ck) {
    // prefetch chunk ck+1 into registers (overlaps with compute below)
    if (ck < 15) {
      const int nn0 = (ck + 1)*64;
#pragma unroll
      for (int i = 0; i < 2; ++i) {
        const int c = i*256 + tid;
        gk[i] = *(const bf16x8*)(kbh + (size_t)(nn0 + (c >> 3))*HD + (c & 7)*8);
        gv[i] = *(const bf16x8*)(vbh + (size_t)(c >> 3)*HN + nn0 + (c & 7)*8);
      }
    }

    // S = Q K^T : 16 MFMAs (2 m-tiles x 2 kk x 4 nt)
    f32x4 sacc[2][4] = {};
#pragma unroll
    for (int kk = 0; kk < 2; ++kk)
#pragma unroll
      for (int nt = 0; nt < 4; ++nt) {
        bf16x8 bk = *(const bf16x8*)(&Ks[nt*16 + lc][kk*32 + quad*8]);
#pragma unroll
        for (int mt = 0; mt < 2; ++mt)
          sacc[mt][nt] = mfma16(aq[mt][kk], bk, sacc[mt][nt]);
      }

    // fixed-max softmax + P stash (C->A relayout, ds_write_b64 per row)
#pragma unroll
    for (int mt = 0; mt < 2; ++mt)
#pragma unroll
      for (int r = 0; r < 4; ++r) {
        float ps[4];
#pragma unroll
        for (int nt = 0; nt < 4; ++nt) {
          ps[nt] = fast_exp2(__builtin_fmaf(sacc[mt][nt][r], LOG2E, -MB2));
          sacc[mt][nt][r] = ps[nt];
        }
        l_i[mt][r] += (ps[0] + ps[1]) + (ps[2] + ps[3]);
        uint2 pk;
        pk.x = pack_bf16_rne(ps[0], ps[1]);
        pk.y = pack_bf16_rne(ps[2], ps[3]);
        *(uint2*)(&Ps[w][mt*16 + quad*4 + r][lc*4]) = pk;
      }

    // O += P V : 16 MFMAs (A from Ps, B from Vts; both in permuted key space)
#pragma unroll
    for (int kk = 0; kk < 2; ++kk) {
      bf16x8 ap[2];
#pragma unroll
      for (int mt = 0; mt < 2; ++mt)
        ap[mt] = *(const bf16x8*)(&Ps[w][mt*16 + lc][kk*32 + quad*8]);
#pragma unroll
      for (int nt2 = 0; nt2 < 4; ++nt2) {
        bf16x8 bv = *(const bf16x8*)(&Vts[nt2*16 + lc][kk*32 + quad*8]);
#pragma unroll
        for (int mt = 0; mt < 2; ++mt)
          oacc[mt][nt2] = mfma16(ap[mt], bv, oacc[mt][nt2]);
      }
    }

    if (ck < 15) {
      __syncthreads();   // all waves done reading Ks/Vts
#pragma unroll
      for (int i = 0; i < 2; ++i) {
        const int c = i*256 + tid;
        *(bf16x8*)(&Ks [c >> 3][(c & 7)*8]) = gk[i];
        *(bf16x8*)(&Vts[c >> 3][(c & 7)*8]) = gv[i];
      }
      __syncthreads();
    }
  }

  // epilogue: reduce l across the 16 lanes of each quad, then scale & store
#pragma unroll
  for (int mt = 0; mt < 2; ++mt)
#pragma unroll
    for (int r = 0; r < 4; ++r) {
      float l = l_i[mt][r];
#pragma unroll
      for (int off = 1; off < 16; off <<= 1) l += __shfl_xor(l, off);
      const float rl = 1.0f / l;
      const int row = qt*128 + w*32 + mt*16 + quad*4 + r;
#pragma unroll
      for (int nt2 = 0; nt2 < 4; ++nt2) {
        const int d = nt2*16 + lc;
        AOb[((size_t)(b*HN + row))*HC + h*HD + d] = f2bf(oacc[mt][nt2][r] * rl);
      }
    }
}

// ---------------- launch ----------------
extern "C" void kernel_launch(void* const* d_in, const int* in_sizes, int n_in,
                              void* d_out, int out_size, void* d_ws, size_t ws_size,
                              hipStream_t stream) {
  const float* x     = (const float*)d_in[0];
  const float* wqkv  = (const float*)d_in[1];
  const float* wproj = (const float*)d_in[2];
  float* out = (float*)d_out;

  char* ws = (char*)d_ws;
  size_t off = 0;
  auto alloc = [&](size_t bytes) -> void* {
    void* p = ws + off; off += (bytes + 255) & ~(size_t)255; return p;
  };
  short* xb     = (short*)alloc((size_t)ROWS*HC*2);        // 12.6 MB
  short* wqkvb  = (short*)alloc((size_t)3*HC*HC*2);        //  3.5 MB
  short* wprojb = (short*)alloc((size_t)HC*HC*2);          //  1.2 MB
  short* Qb     = (short*)alloc((size_t)BH*HN*HD*2);       // 12.6 MB
  short* Kb     = (short*)alloc((size_t)BH*HN*HD*2);       // 12.6 MB
  short* Vtb    = (short*)alloc((size_t)BH*HD*HN*2);       // 12.6 MB
  short* AOb    = (short*)alloc((size_t)ROWS*HC*2);        // 12.6 MB  (~68 MB total)

  { const int n0 = ROWS*HC/4, n1 = 3*HC*HC/4, n2 = HC*HC/4;
    const int tot = n0 + n1 + n2;
    cvt3_kernel<<<(tot + 255)/256, 256, 0, stream>>>(x, xb, n0, wqkv, wqkvb, n1,
                                                     wproj, wprojb, n2); }

  // 576 = 32 m-blocks x 18 n-blocks, XCD-swizzled inside the kernel
  gemm_qkv<<<dim3(576), 512, 0, stream>>>(xb, wqkvb, Qb, Kb, Vtb);
  attn_kernel<<<BH*8, 256, 0, stream>>>(Qb, Kb, Vtb, AOb);
  gemm_bt_f32<<<dim3(HC/128, ROWS/128), 256, 0, stream>>>(AOb, wprojb, out,
                                                          ROWS, HC, HC);
}

// Round 6
// 180.644 us; speedup vs baseline: 1.1324x; 1.0107x over previous
//
#include <hip/hip_runtime.h>
#include <stdint.h>
#include <stddef.h>

// Problem constants
#define HB 8
#define HN 1024
#define HC 768
#define HH 12
#define HD 64
#define ROWS (HB*HN)      // 8192
#define BH (HB*HH)        // 96

using s16x4  = __attribute__((ext_vector_type(4))) short;
using bf16x8 = __attribute__((ext_vector_type(8))) short;
using f32x4  = __attribute__((ext_vector_type(4))) float;

__device__ __forceinline__ short f2bf(float f) {
  union { float f; uint32_t u; } c; c.f = f;
  uint32_t u = c.u;
  uint32_t r = (u + 0x7fffu + ((u >> 16) & 1u)) >> 16;   // RNE
  return (short)r;
}
__device__ __forceinline__ float bf2f(short s) {
  union { uint32_t u; float f; } c; c.u = ((uint32_t)(uint16_t)s) << 16;
  return c.f;
}
// pack two f32 -> {bf16(a) | bf16(b)<<16} with RNE, via v_perm_b32
__device__ __forceinline__ uint32_t pack_bf16_rne(float a, float b) {
  union { float f; uint32_t u; } ca, cb; ca.f = a; cb.f = b;
  uint32_t ra = ca.u + 0x7fffu + ((ca.u >> 16) & 1u);
  uint32_t rb = cb.u + 0x7fffu + ((cb.u >> 16) & 1u);
  return __builtin_amdgcn_perm(rb, ra, 0x07060302);  // {rb[31:16], ra[31:16]}
}
__device__ __forceinline__ float fast_exp2(float x) {
#if __has_builtin(__builtin_amdgcn_exp2f)
  return __builtin_amdgcn_exp2f(x);
#else
  return exp2f(x);
#endif
}
__device__ __forceinline__ f32x4 mfma16(bf16x8 a, bf16x8 b, f32x4 c) {
  return __builtin_amdgcn_mfma_f32_16x16x32_bf16(a, b, c, 0, 0, 0);
}
// async global->LDS, 16B per lane. LDS dest MUST be wave-uniform base + lane*16.
__device__ __forceinline__ void gll16(const void* g, void* l) {
  __builtin_amdgcn_global_load_lds((const __attribute__((address_space(1))) void*)g,
                                   (__attribute__((address_space(3))) void*)l,
                                   16, 0, 0);
}

// ---------------- fused f32 -> bf16 convert for all 3 inputs ----------------
__global__ void cvt3_kernel(const float* __restrict__ x,  short* __restrict__ xb,  int n0,
                            const float* __restrict__ wq, short* __restrict__ wqb, int n1,
                            const float* __restrict__ wp, short* __restrict__ wpb, int n2) {
  int i = blockIdx.x * 256 + threadIdx.x;        // index in float4 units
  const float* in; short* out;
  if (i < n0)            { in = x;  out = xb;  }
  else if (i < n0 + n1)  { i -= n0; in = wq; out = wqb; }
  else if (i < n0 + n1 + n2) { i -= n0 + n1; in = wp; out = wpb; }
  else return;
  float4 v = ((const float4*)in)[i];
  s16x4 o;
  o.x = f2bf(v.x); o.y = f2bf(v.y); o.z = f2bf(v.z); o.w = f2bf(v.w);
  ((s16x4*)out)[i] = o;
}

// ---------------- GEMM 1: qkv = x*Wqkv^T ------------------------------------
// R11 pipeline (proven): BM=256 BN=128 BK=32, 512 thr (8 waves, 4Mx2N),
// 3 LDS slots, 2-deep staging, one barrier + one vmcnt(3) per K-tile.
// R12: v-epilogue writes Vtb DIRECTLY (key-permuted transpose via LDS reuse).
template<int VM, bool STG, int SLOT>
__device__ __forceinline__ void qkv_ktile(
    int kt, short* sA, short* sB,
    const short* Ag, const short* Bg,
    int wr, int wc, int quad, int lc,
    int aoff0, int aoff1, int boff0,      // per-thread source offsets (row*HC+swz-col)
    int cA0, int cA1, int cB0,            // per-thread LDS chunk ids
    f32x4 (&acc)[4][4])
{
  // T(kt) landed for THIS wave; barrier makes it true for ALL waves.
  if constexpr (VM == 3) asm volatile("s_waitcnt vmcnt(3)" ::: "memory");
  else                   asm volatile("s_waitcnt vmcnt(0)" ::: "memory");
  __builtin_amdgcn_s_barrier();
  // After the barrier every wave finished iteration kt-1 (incl. its ds_reads
  // of slot (kt-1)%3) -> safe to stage kt+2 into that slot.
  if constexpr (STG) {
    constexpr int DST = (SLOT + 2) % 3;
    const int kcol = (kt + 2) * 32;
    short* dA = sA + DST*8192;
    short* dB = sB + DST*4096;
    gll16(Ag + (size_t)(aoff0 + kcol), (void*)(dA + cA0*8));
    gll16(Ag + (size_t)(aoff1 + kcol), (void*)(dA + cA1*8));
    gll16(Bg + (size_t)(boff0 + kcol), (void*)(dB + cB0*8));
  }
  const short* sa = sA + SLOT*8192;
  const short* sb = sB + SLOT*4096;
  bf16x8 af[4], bfr[4];
#pragma unroll
  for (int mt = 0; mt < 4; ++mt) {
    const int rA = wr*64 + mt*16 + lc;
    af[mt] = *(const bf16x8*)(sa + rA*32 + (quad ^ ((rA >> 1) & 3))*8);
  }
#pragma unroll
  for (int nt = 0; nt < 4; ++nt) {
    const int rB = wc*64 + nt*16 + lc;
    bfr[nt] = *(const bf16x8*)(sb + rB*32 + (quad ^ ((rB >> 1) & 3))*8);
  }
  __builtin_amdgcn_s_setprio(1);
#pragma unroll
  for (int mt = 0; mt < 4; ++mt)
#pragma unroll
    for (int nt = 0; nt < 4; ++nt)
      acc[mt][nt] = mfma16(af[mt], bfr[nt], acc[mt][nt]);
  __builtin_amdgcn_s_setprio(0);
}

__global__ __launch_bounds__(512, 4) void gemm_qkv(const short* __restrict__ A,
                                                   const short* __restrict__ Bw,
                                                   short* __restrict__ Qb,
                                                   short* __restrict__ Kb,
                                                   short* __restrict__ Vtb) {
  __shared__ short SMEM[3*256*32 + 3*128*32];   // 72 KiB, reused by v-epilogue
  short* As = SMEM;                 // 3 x [256][32]
  short* Bs = SMEM + 3*256*32;      // 3 x [128][32]
  // XCD-bijective swizzle: 576 wgs = 8 XCDs x 72 (4 m-panels x 18 n) each.
  const int wg = blockIdx.x;
  const int swz = (wg & 7)*72 + (wg >> 3);
  const int by = swz / 18, bx = swz % 18;
  const int m0 = by*256, n0 = bx*128;
  const int tid = threadIdx.x;
  const int lane = tid & 63, w = tid >> 6, quad = lane >> 4, lc = lane & 15;
  const int wr = w >> 1, wc = w & 1;           // 4 x 2 wave grid
  // staging: A tile 256x32 = 1024 16B-chunks (2/thread); B 128x32 = 512 (1/thread)
  // chunk c: r = c>>2, cb = c&3; source col pre-swizzled cb ^ ((r>>1)&3)
  const int cA0 = tid,        rA0 = cA0 >> 2, sbA0 = ((cA0 & 3) ^ ((rA0 >> 1) & 3))*8;
  const int cA1 = 512 + tid,  rA1 = cA1 >> 2, sbA1 = ((cA1 & 3) ^ ((rA1 >> 1) & 3))*8;
  const int cB0 = tid,        rB0 = cB0 >> 2, sbB0 = ((cB0 & 3) ^ ((rB0 >> 1) & 3))*8;
  const int aoff0 = rA0*HC + sbA0;
  const int aoff1 = rA1*HC + sbA1;
  const int boff0 = rB0*HC + sbB0;
  const short* Ag = A  + (size_t)m0*HC;
  const short* Bg = Bw + (size_t)n0*HC;
  f32x4 acc[4][4] = {};

  // prologue: stage K-tiles 0 and 1 (FIFO order: T0's 3 loads, then T1's 3)
#pragma unroll
  for (int pk = 0; pk < 2; ++pk) {
    gll16(Ag + (size_t)(aoff0 + pk*32), (void*)(As + pk*8192 + cA0*8));
    gll16(Ag + (size_t)(aoff1 + pk*32), (void*)(As + pk*8192 + cA1*8));
    gll16(Bg + (size_t)(boff0 + pk*32), (void*)(Bs + pk*4096 + cB0*8));
  }

  // main loop: 24 K-tiles, unrolled by 3 so the slot index is compile-time
#pragma unroll 1
  for (int kt = 0; kt < 21; kt += 3) {
    qkv_ktile<3,true,0>(kt,   As, Bs, Ag, Bg, wr, wc, quad, lc,
                        aoff0, aoff1, boff0, cA0, cA1, cB0, acc);
    qkv_ktile<3,true,1>(kt+1, As, Bs, Ag, Bg, wr, wc, quad, lc,
                        aoff0, aoff1, boff0, cA0, cA1, cB0, acc);
    qkv_ktile<3,true,2>(kt+2, As, Bs, Ag, Bg, wr, wc, quad, lc,
                        aoff0, aoff1, boff0, cA0, cA1, cB0, acc);
  }
  qkv_ktile<3,true ,0>(21, As, Bs, Ag, Bg, wr, wc, quad, lc,
                       aoff0, aoff1, boff0, cA0, cA1, cB0, acc);   // stages T23
  qkv_ktile<3,false,1>(22, As, Bs, Ag, Bg, wr, wc, quad, lc,
                       aoff0, aoff1, boff0, cA0, cA1, cB0, acc);
  qkv_ktile<0,false,2>(23, As, Bs, Ag, Bg, wr, wc, quad, lc,
                       aoff0, aoff1, boff0, cA0, cA1, cB0, acc);

  // epilogue (C/D: col=nt*16+lc, row=quad*4+r); per-wave 64-col group = 1 head
  const int cg = n0 + wc*64;
  const int t = cg / HC;                // 0=q, 1=k, 2=v (block-uniform: n0 % 128 == 0)
  const int h = (cg % HC) / HD;
  if (t < 2) {
    short* outp = (t == 0) ? Qb : Kb;
    const float sc = (t == 0) ? 0.125f : 1.0f;   // SCALE = 64^-0.5 for q
#pragma unroll
    for (int i = 0; i < 4; ++i)
#pragma unroll
      for (int r = 0; r < 4; ++r) {
        float s1 = (acc[i][0][r] + acc[i][1][r]) + (acc[i][2][r] + acc[i][3][r]);
        float s2 = acc[i][0][r]*acc[i][0][r];
        s2 = __builtin_fmaf(acc[i][1][r], acc[i][1][r], s2);
        s2 = __builtin_fmaf(acc[i][2][r], acc[i][2][r], s2);
        s2 = __builtin_fmaf(acc[i][3][r], acc[i][3][r], s2);
#pragma unroll
        for (int off = 1; off < 16; off <<= 1) {
          s1 += __shfl_xor(s1, off);
          s2 += __shfl_xor(s2, off);
        }
        const float mean = s1 * (1.0f/64.0f);
        const float var  = s2 * (1.0f/64.0f) - mean*mean;
        const float inv  = rsqrtf(var + 1e-5f) * sc;
        const int row = m0 + wr*64 + i*16 + quad*4 + r;
        const int b = row >> 10, n_in = row & 1023;
        short* rowp = outp + ((size_t)(b*HH + h)*HN + n_in)*HD;
#pragma unroll
        for (int nt = 0; nt < 4; ++nt)
          rowp[nt*16 + lc] = f2bf((acc[i][nt][r] - mean) * inv);
      }
  } else {
    // fused V-transpose: acc -> LDS (key-permuted, stride 268) -> Vtb.
    // Storage col c holds key k: c(k) = ((k&15)<<2)|(k>>4); inverse of
    // vtrans's perm(c) = (c&3)*16 + (c>>2)  [perm(c(k)) == k].
    short* vs = SMEM;                 // [2][64][268] = 34304 shorts <= 36864
    __syncthreads();                  // main-loop LDS fully consumed by all waves
    const int hd = wc;                // wave's head slot (0/1)
#pragma unroll
    for (int i = 0; i < 4; ++i)
#pragma unroll
      for (int nt = 0; nt < 4; ++nt)
#pragma unroll
        for (int r = 0; r < 4; ++r) {
          const int dd = nt*16 + lc;
          const int k  = i*16 + quad*4 + r;            // row within 64-group
          const int c  = ((k & 15) << 2) | (k >> 4);   // permuted col
          vs[(hd*64 + dd)*268 + wr*64 + c] = f2bf(acc[i][nt][r]);
        }
    __syncthreads();
    const int b = m0 >> 10, m0g = m0 & 1023;
#pragma unroll
    for (int it = 0; it < 8; ++it) {
      const int idx = it*512 + tid;        // [0,4096)
      const int h2 = idx >> 11;            // head slot 0/1
      const int rem = idx & 2047;
      const int dd = rem >> 5, c8 = rem & 31;
      const int habs = ((n0 + h2*64) - 1536) >> 6;     // absolute head
      const short* src = vs + (h2*64 + dd)*268 + c8*8; // 8B-aligned
      s16x4 lo = *(const s16x4*)(src);
      s16x4 hi = *(const s16x4*)(src + 4);
      bf16x8 vvv;
      vvv[0]=lo[0]; vvv[1]=lo[1]; vvv[2]=lo[2]; vvv[3]=lo[3];
      vvv[4]=hi[0]; vvv[5]=hi[1]; vvv[6]=hi[2]; vvv[7]=hi[3];
      *(bf16x8*)(Vtb + ((size_t)((b*HH + habs)*HD + dd))*HN + m0g + c8*8) = vvv;
    }
  }
}

// ---------------- GEMM 2: out = AO * Wproj^T (f32 out) ----------------------
// R14: ported to the R11 counted-vmcnt pipeline. BM=128 BN=128 BK=32,
// 256 thr (4 waves, 2Mx2N), per-wave 64x64 acc[4][4] (same as gemm_qkv's).
// 3 LDS slots x (A 8KB + B 8KB) = 48 KiB -> 3 blocks/CU; grid 384 = 64m x 6n
// <= 768 resident capacity -> whole grid co-resident, zero quantization tail.
// Uniform 4 loads/thread/K-tile (2A+2B) -> single vmcnt(4); drains only at tail.
template<int VM, bool STG, int SLOT>
__device__ __forceinline__ void bt_ktile(
    int kt, short* sA, short* sB,
    const short* Ag, const short* Bg,
    int wr, int wc, int quad, int lc,
    int aoff0, int aoff1, int boff0, int boff1,
    int cA0, int cA1, int cB0, int cB1,
    f32x4 (&acc)[4][4])
{
  if constexpr (VM == 4) asm volatile("s_waitcnt vmcnt(4)" ::: "memory");
  else                   asm volatile("s_waitcnt vmcnt(0)" ::: "memory");
  __builtin_amdgcn_s_barrier();
  if constexpr (STG) {
    constexpr int DST = (SLOT + 2) % 3;
    const int kcol = (kt + 2) * 32;
    short* dA = sA + DST*4096;
    short* dB = sB + DST*4096;
    gll16(Ag + (size_t)(aoff0 + kcol), (void*)(dA + cA0*8));
    gll16(Ag + (size_t)(aoff1 + kcol), (void*)(dA + cA1*8));
    gll16(Bg + (size_t)(boff0 + kcol), (void*)(dB + cB0*8));
    gll16(Bg + (size_t)(boff1 + kcol), (void*)(dB + cB1*8));
  }
  const short* sa = sA + SLOT*4096;
  const short* sb = sB + SLOT*4096;
  bf16x8 af[4], bfr[4];
#pragma unroll
  for (int mt = 0; mt < 4; ++mt) {
    const int rA = wr*64 + mt*16 + lc;
    af[mt] = *(const bf16x8*)(sa + rA*32 + (quad ^ ((rA >> 1) & 3))*8);
  }
#pragma unroll
  for (int nt = 0; nt < 4; ++nt) {
    const int rB = wc*64 + nt*16 + lc;
    bfr[nt] = *(const bf16x8*)(sb + rB*32 + (quad ^ ((rB >> 1) & 3))*8);
  }
  __builtin_amdgcn_s_setprio(1);
#pragma unroll
  for (int mt = 0; mt < 4; ++mt)
#pragma unroll
    for (int nt = 0; nt < 4; ++nt)
      acc[mt][nt] = mfma16(af[mt], bfr[nt], acc[mt][nt]);
  __builtin_amdgcn_s_setprio(0);
}

__global__ __launch_bounds__(256, 3) void gemm_bt_f32(const short* __restrict__ A,
                                                      const short* __restrict__ Bw,
                                                      float* __restrict__ C) {
  __shared__ short As[3*128*32];   // 24 KiB
  __shared__ short Bs[3*128*32];   // 24 KiB
  // XCD swizzle: 384 wgs = 8 XCDs x 48 (8 m-panels x 6 n) each.
  const int wg = blockIdx.x;
  const int swz = (wg & 7)*48 + (wg >> 3);
  const int by = swz / 6, bx = swz % 6;
  const int m0 = by*128, n0 = bx*128;
  const int tid = threadIdx.x;
  const int lane = tid & 63, w = tid >> 6, quad = lane >> 4, lc = lane & 15;
  const int wr = w >> 1, wc = w & 1;           // 2 x 2 wave grid
  // staging: A,B tiles 128x32 = 512 16B-chunks each (2/thread each)
  const int cA0 = tid,        rA0 = cA0 >> 2, sbA0 = ((cA0 & 3) ^ ((rA0 >> 1) & 3))*8;
  const int cA1 = 256 + tid,  rA1 = cA1 >> 2, sbA1 = ((cA1 & 3) ^ ((rA1 >> 1) & 3))*8;
  const int aoff0 = rA0*HC + sbA0;
  const int aoff1 = rA1*HC + sbA1;
  const int cB0 = cA0, cB1 = cA1;
  const int boff0 = aoff0, boff1 = aoff1;      // same mapping, B base differs
  const short* Ag = A  + (size_t)m0*HC;
  const short* Bg = Bw + (size_t)n0*HC;
  f32x4 acc[4][4] = {};

  // prologue: stage K-tiles 0 and 1 (FIFO per tile: A,A,B,B)
#pragma unroll
  for (int pk = 0; pk < 2; ++pk) {
    gll16(Ag + (size_t)(aoff0 + pk*32), (void*)(As + pk*4096 + cA0*8));
    gll16(Ag + (size_t)(aoff1 + pk*32), (void*)(As + pk*4096 + cA1*8));
    gll16(Bg + (size_t)(boff0 + pk*32), (void*)(Bs + pk*4096 + cB0*8));
    gll16(Bg + (size_t)(boff1 + pk*32), (void*)(Bs + pk*4096 + cB1*8));
  }

#pragma unroll 1
  for (int kt = 0; kt < 21; kt += 3) {
    bt_ktile<4,true,0>(kt,   As, Bs, Ag, Bg, wr, wc, quad, lc,
                       aoff0, aoff1, boff0, boff1, cA0, cA1, cB0, cB1, acc);
    bt_ktile<4,true,1>(kt+1, As, Bs, Ag, Bg, wr, wc, quad, lc,
                       aoff0, aoff1, boff0, boff1, cA0, cA1, cB0, cB1, acc);
    bt_ktile<4,true,2>(kt+2, As, Bs, Ag, Bg, wr, wc, quad, lc,
                       aoff0, aoff1, boff0, boff1, cA0, cA1, cB0, cB1, acc);
  }
  bt_ktile<4,true ,0>(21, As, Bs, Ag, Bg, wr, wc, quad, lc,
                      aoff0, aoff1, boff0, boff1, cA0, cA1, cB0, cB1, acc);  // stages T23
  bt_ktile<4,false,1>(22, As, Bs, Ag, Bg, wr, wc, quad, lc,
                      aoff0, aoff1, boff0, boff1, cA0, cA1, cB0, cB1, acc);
  bt_ktile<0,false,2>(23, As, Bs, Ag, Bg, wr, wc, quad, lc,
                      aoff0, aoff1, boff0, boff1, cA0, cA1, cB0, cB1, acc);

#pragma unroll
  for (int mt = 0; mt < 4; ++mt)
#pragma unroll
    for (int nt = 0; nt < 4; ++nt)
#pragma unroll
      for (int r = 0; r < 4; ++r) {
        const int row = m0 + wr*64 + mt*16 + quad*4 + r;
        const int col = n0 + wc*64 + nt*16 + lc;
        C[(size_t)row*HC + col] = acc[mt][nt][r];
      }
}

// ---------------- flash attention: 128 q-rows/block, 64-key chunks ----------
// R9 structure; R13: XCD-grouped block swizzle (all 8 q-tiles of each bh on
// one XCD -> per-XCD K/V working set 12*256KB = 3MB fits the 4MB L2).
__global__ __launch_bounds__(256, 3) void attn_kernel(const short* __restrict__ Qb,
                                                      const short* __restrict__ Kb,
                                                      const short* __restrict__ Vtb,
                                                      short* __restrict__ AOb) {
  const int raw = blockIdx.x;
  const int blk = (raw & 7)*96 + (raw >> 3);   // bijective on [0,768)
  const int qt = blk & 7, bh = blk >> 3;
  const int b = bh / HH, h = bh % HH;
  const int tid = threadIdx.x, w = tid >> 6, lane = tid & 63;
  const int quad = lane >> 4, lc = lane & 15;

  __shared__ short Ks [64][72];      // K chunk: row=key(natural), padded
  __shared__ short Vts[64][72];      // V chunk: row=d, cols=64 keys permuted
  __shared__ short Ps [4][32][72];   // per-wave P stash (32 q-rows), permuted keys

  // Q A-fragments: A[m=lane&15][k=quad*8+j]; wave rows qt*128 + w*32 + mt*16
  bf16x8 aq[2][2];
#pragma unroll
  for (int mt = 0; mt < 2; ++mt) {
    const int mrow = qt*128 + w*32 + mt*16 + lc;
    aq[mt][0] = *(const bf16x8*)(Qb + ((size_t)bh*HN + mrow)*HD + quad*8);
    aq[mt][1] = *(const bf16x8*)(Qb + ((size_t)bh*HN + mrow)*HD + 32 + quad*8);
  }

  const short* kbh = Kb  + (size_t)bh*HN*HD;
  const short* vbh = Vtb + (size_t)bh*HD*HN;

  f32x4 oacc[2][4] = {};
  float l_i[2][4] = {};

  // staging regs: c = i*256+tid in [0,512); row=c>>3 in [0,64), cb=c&7
  bf16x8 gk[2], gv[2];
#pragma unroll
  for (int i = 0; i < 2; ++i) {
    const int c = i*256 + tid;
    gk[i] = *(const bf16x8*)(kbh + (size_t)(c >> 3)*HD + (c & 7)*8);
    gv[i] = *(const bf16x8*)(vbh + (size_t)(c >> 3)*HN + (c & 7)*8);
  }
#pragma unroll
  for (int i = 0; i < 2; ++i) {
    const int c = i*256 + tid;
    *(bf16x8*)(&Ks [c >> 3][(c & 7)*8]) = gk[i];
    *(bf16x8*)(&Vts[c >> 3][(c & 7)*8]) = gv[i];
  }
  __syncthreads();

  const float LOG2E = 1.44269504f;
  const float MB2   = 8.0f * 1.44269504f;   // fixed max * log2(e)

  for (int ck = 0; ck < 16; ++ck) {
    // prefetch chunk ck+1 into registers (overlaps with compute below)
    if (ck < 15) {
      const int nn0 = (ck + 1)*64;
#pragma unroll
      for (int i = 0; i < 2; ++i) {
        const int c = i*256 + tid;
        gk[i] = *(const bf16x8*)(kbh + (size_t)(nn0 + (c >> 3))*HD + (c & 7)*8);
        gv[i] = *(const bf16x8*)(vbh + (size_t)(c >> 3)*HN + nn0 + (c & 7)*8);
      }
    }

    // S = Q K^T : 16 MFMAs (2 m-tiles x 2 kk x 4 nt)
    f32x4 sacc[2][4] = {};
#pragma unroll
    for (int kk = 0; kk < 2; ++kk)
#pragma unroll
      for (int nt = 0; nt < 4; ++nt) {
        bf16x8 bk = *(const bf16x8*)(&Ks[nt*16 + lc][kk*32 + quad*8]);
#pragma unroll
        for (int mt = 0; mt < 2; ++mt)
          sacc[mt][nt] = mfma16(aq[mt][kk], bk, sacc[mt][nt]);
      }

    // fixed-max softmax + P stash (C->A relayout, ds_write_b64 per row)
#pragma unroll
    for (int mt = 0; mt < 2; ++mt)
#pragma unroll
      for (int r = 0; r < 4; ++r) {
        float ps[4];
#pragma unroll
        for (int nt = 0; nt < 4; ++nt) {
          ps[nt] = fast_exp2(__builtin_fmaf(sacc[mt][nt][r], LOG2E, -MB2));
          sacc[mt][nt][r] = ps[nt];
        }
        l_i[mt][r] += (ps[0] + ps[1]) + (ps[2] + ps[3]);
        uint2 pk;
        pk.x = pack_bf16_rne(ps[0], ps[1]);
        pk.y = pack_bf16_rne(ps[2], ps[3]);
        *(uint2*)(&Ps[w][mt*16 + quad*4 + r][lc*4]) = pk;
      }

    // O += P V : 16 MFMAs (A from Ps, B from Vts; both in permuted key space)
#pragma unroll
    for (int kk = 0; kk < 2; ++kk) {
      bf16x8 ap[2];
#pragma unroll
      for (int mt = 0; mt < 2; ++mt)
        ap[mt] = *(const bf16x8*)(&Ps[w][mt*16 + lc][kk*32 + quad*8]);
#pragma unroll
      for (int nt2 = 0; nt2 < 4; ++nt2) {
        bf16x8 bv = *(const bf16x8*)(&Vts[nt2*16 + lc][kk*32 + quad*8]);
#pragma unroll
        for (int mt = 0; mt < 2; ++mt)
          oacc[mt][nt2] = mfma16(ap[mt], bv, oacc[mt][nt2]);
      }
    }

    if (ck < 15) {
      __syncthreads();   // all waves done reading Ks/Vts
#pragma unroll
      for (int i = 0; i < 2; ++i) {
        const int c = i*256 + tid;
        *(bf16x8*)(&Ks [c >> 3][(c & 7)*8]) = gk[i];
        *(bf16x8*)(&Vts[c >> 3][(c & 7)*8]) = gv[i];
      }
      __syncthreads();
    }
  }

  // epilogue: reduce l across the 16 lanes of each quad, then scale & store
#pragma unroll
  for (int mt = 0; mt < 2; ++mt)
#pragma unroll
    for (int r = 0; r < 4; ++r) {
      float l = l_i[mt][r];
#pragma unroll
      for (int off = 1; off < 16; off <<= 1) l += __shfl_xor(l, off);
      const float rl = 1.0f / l;
      const int row = qt*128 + w*32 + mt*16 + quad*4 + r;
#pragma unroll
      for (int nt2 = 0; nt2 < 4; ++nt2) {
        const int d = nt2*16 + lc;
        AOb[((size_t)(b*HN + row))*HC + h*HD + d] = f2bf(oacc[mt][nt2][r] * rl);
      }
    }
}

// ---------------- launch ----------------
extern "C" void kernel_launch(void* const* d_in, const int* in_sizes, int n_in,
                              void* d_out, int out_size, void* d_ws, size_t ws_size,
                              hipStream_t stream) {
  const float* x     = (const float*)d_in[0];
  const float* wqkv  = (const float*)d_in[1];
  const float* wproj = (const float*)d_in[2];
  float* out = (float*)d_out;

  char* ws = (char*)d_ws;
  size_t off = 0;
  auto alloc = [&](size_t bytes) -> void* {
    void* p = ws + off; off += (bytes + 255) & ~(size_t)255; return p;
  };
  short* xb     = (short*)alloc((size_t)ROWS*HC*2);        // 12.6 MB
  short* wqkvb  = (short*)alloc((size_t)3*HC*HC*2);        //  3.5 MB
  short* wprojb = (short*)alloc((size_t)HC*HC*2);          //  1.2 MB
  short* Qb     = (short*)alloc((size_t)BH*HN*HD*2);       // 12.6 MB
  short* Kb     = (short*)alloc((size_t)BH*HN*HD*2);       // 12.6 MB
  short* Vtb    = (short*)alloc((size_t)BH*HD*HN*2);       // 12.6 MB
  short* AOb    = (short*)alloc((size_t)ROWS*HC*2);        // 12.6 MB  (~68 MB total)

  { const int n0 = ROWS*HC/4, n1 = 3*HC*HC/4, n2 = HC*HC/4;
    const int tot = n0 + n1 + n2;
    cvt3_kernel<<<(tot + 255)/256, 256, 0, stream>>>(x, xb, n0, wqkv, wqkvb, n1,
                                                     wproj, wprojb, n2); }

  // 576 = 32 m-blocks x 18 n-blocks, XCD-swizzled inside the kernel
  gemm_qkv<<<dim3(576), 512, 0, stream>>>(xb, wqkvb, Qb, Kb, Vtb);
  attn_kernel<<<BH*8, 256, 0, stream>>>(Qb, Kb, Vtb, AOb);
  // 384 = 64 m-blocks x 6 n-blocks, XCD-swizzled inside the kernel
  gemm_bt_f32<<<dim3(384), 256, 0, stream>>>(AOb, wprojb, out);
}